// Round 1
// baseline (2208.926 us; speedup 1.0000x reference)
//
#include <hip/hip_runtime.h>

#define NK 512
#define SUBD 256
#define TT 2048
#define BD 512
#define NBATCH 32
#define NROWS 65536
#define DECAYF 0.99f
#define OMDF 0.01f
#define EPSF 1e-5f
#define FLT_BIG 3.402823466e+38f

// ---------------- kernel P0: sume2[h][k] = sum_c emb[k][c]^2 ----------------
__global__ __launch_bounds__(256) void vq_sume2(const float* __restrict__ emb1,
                                                const float* __restrict__ emb2,
                                                float* __restrict__ sume2) {
    int r = blockIdx.x * 256 + threadIdx.x;   // 0..1023
    const float* e = (r >> 9) ? emb2 : emb1;
    const float* row = e + (size_t)(r & 511) * SUBD;
    float s = 0.f;
#pragma unroll 8
    for (int i = 0; i < 64; ++i) {
        float4 v = *reinterpret_cast<const float4*>(row + i * 4);
        s += v.x * v.x + v.y * v.y + v.z * v.z + v.w * v.w;
    }
    sume2[r] = s;
}

// ---------------- kernel A: argmin + counts + dw ----------------
// grid 1024 = (b, t-chunk of 64); block 256 = 16 ti (4 t each) x 16 tj (4 k each)
__global__ __launch_bounds__(256, 2) void vq_argmin(const float* __restrict__ x,
                                                    const float* __restrict__ emb1,
                                                    const float* __restrict__ emb2,
                                                    const float* __restrict__ sume2,
                                                    float* __restrict__ counts,
                                                    float* __restrict__ dw,
                                                    int* __restrict__ idx_out) {
    __shared__ float xs[256 * 64];     // [c'][t]  64 KB
    __shared__ float es[32 * 68];      // [cc][kk] padded to 68 (16B-aligned rows)
    __shared__ int   idx_l[64];

    const int tid = threadIdx.x;
    const int b = blockIdx.x >> 5;
    const int t0 = (blockIdx.x & 31) << 6;
    const int ti = tid >> 4;   // 0..15 -> owns t = ti*4..+3
    const int tj = tid & 15;   // 0..15 -> owns k = tj*4..+3 per k-tile
    const float* xbase = x + (size_t)b * BD * TT + t0;

    for (int h = 0; h < 2; ++h) {
        const float* embp = h ? emb2 : emb1;
        __syncthreads();   // protect xs/idx_l from previous half's readers
        // ---- load full half x-tile: xs[c'][t], c' in 0..255, t in 0..63 ----
#pragma unroll
        for (int i = 0; i < 16; ++i) {
            int j = tid + i * 256;         // float4 index 0..4095
            int c = j >> 4;
            int f4 = j & 15;
            float4 v = *reinterpret_cast<const float4*>(
                xbase + (size_t)(h * 256 + c) * TT + f4 * 4);
            *reinterpret_cast<float4*>(&xs[c * 64 + f4 * 4]) = v;
        }
        __syncthreads();

        // ---- row norms ||f||^2 for this thread's 4 t's ----
        float f2[4] = {0.f, 0.f, 0.f, 0.f};
#pragma unroll
        for (int s = 0; s < 16; ++s) {
            int cc = tj * 16 + s;
            float4 xv = *reinterpret_cast<const float4*>(&xs[cc * 64 + ti * 4]);
            f2[0] += xv.x * xv.x; f2[1] += xv.y * xv.y;
            f2[2] += xv.z * xv.z; f2[3] += xv.w * xv.w;
        }
#pragma unroll
        for (int m = 1; m < 16; m <<= 1) {
#pragma unroll
            for (int i = 0; i < 4; ++i) f2[i] += __shfl_xor(f2[i], m);
        }

        float bd[4] = {FLT_BIG, FLT_BIG, FLT_BIG, FLT_BIG};
        int   bk[4] = {0, 0, 0, 0};

        for (int kt = 0; kt < 8; ++kt) {
            const int k0 = kt * 64;
            float se[4];
#pragma unroll
            for (int j = 0; j < 4; ++j) se[j] = sume2[(h << 9) + k0 + tj * 4 + j];

            float acc[4][4];
#pragma unroll
            for (int i = 0; i < 4; ++i)
#pragma unroll
                for (int j = 0; j < 4; ++j) acc[i][j] = 0.f;

            for (int ccb = 0; ccb < 8; ++ccb) {
                __syncthreads();
                // stage emb chunk transposed: es[cc][kk]
#pragma unroll
                for (int i = 0; i < 2; ++i) {
                    int j = tid + i * 256;
                    int kk = j >> 3, cc4 = j & 7;
                    float4 v = *reinterpret_cast<const float4*>(
                        embp + (size_t)(k0 + kk) * SUBD + ccb * 32 + cc4 * 4);
                    es[(cc4 * 4 + 0) * 68 + kk] = v.x;
                    es[(cc4 * 4 + 1) * 68 + kk] = v.y;
                    es[(cc4 * 4 + 2) * 68 + kk] = v.z;
                    es[(cc4 * 4 + 3) * 68 + kk] = v.w;
                }
                __syncthreads();
#pragma unroll
                for (int cc = 0; cc < 32; ++cc) {
                    float4 xv = *reinterpret_cast<const float4*>(
                        &xs[(ccb * 32 + cc) * 64 + ti * 4]);
                    float4 ev = *reinterpret_cast<const float4*>(&es[cc * 68 + tj * 4]);
                    acc[0][0] += xv.x * ev.x; acc[0][1] += xv.x * ev.y;
                    acc[0][2] += xv.x * ev.z; acc[0][3] += xv.x * ev.w;
                    acc[1][0] += xv.y * ev.x; acc[1][1] += xv.y * ev.y;
                    acc[1][2] += xv.y * ev.z; acc[1][3] += xv.y * ev.w;
                    acc[2][0] += xv.z * ev.x; acc[2][1] += xv.z * ev.y;
                    acc[2][2] += xv.z * ev.z; acc[2][3] += xv.z * ev.w;
                    acc[3][0] += xv.w * ev.x; acc[3][1] += xv.w * ev.y;
                    acc[3][2] += xv.w * ev.z; acc[3][3] += xv.w * ev.w;
                }
            }
            // distance + best update (replicates ref rounding: (A+B) - 2*fe)
#pragma unroll
            for (int i = 0; i < 4; ++i) {
#pragma unroll
                for (int j = 0; j < 4; ++j) {
                    float ab = f2[i] + se[j];
                    float d = ab - 2.0f * acc[i][j];
                    int kk = k0 + tj * 4 + j;
                    if (d < bd[i]) { bd[i] = d; bk[i] = kk; }
                }
            }
        }
        // ---- reduce (min d, tie -> min k) across the 16 tj lanes ----
#pragma unroll
        for (int m = 1; m < 16; m <<= 1) {
#pragma unroll
            for (int i = 0; i < 4; ++i) {
                float od = __shfl_xor(bd[i], m);
                int   ok = __shfl_xor(bk[i], m);
                if (od < bd[i] || (od == bd[i] && ok < bk[i])) { bd[i] = od; bk[i] = ok; }
            }
        }
        if (tj == 0) {
#pragma unroll
            for (int i = 0; i < 4; ++i) {
                int t = ti * 4 + i;
                idx_out[h * NROWS + b * TT + t0 + t] = bk[i];
                atomicAdd(&counts[(h << 9) + bk[i]], 1.0f);
                idx_l[t] = bk[i];
            }
        }
        __syncthreads();
        // ---- dw scatter from the LDS x-tile ----
        {
            const int lane = tid & 63;
            const int w = tid >> 6;
            const int k = idx_l[lane];
            float* dwr = dw + ((size_t)((h << 9) + k)) * SUBD;
            for (int i = 0; i < 64; ++i) {
                int c = i * 4 + w;
                atomicAdd(&dwr[c], xs[c * 64 + lane]);
            }
        }
    }
}

// ---------------- kernel D1: EMA cluster-size smoothing + perplexity ----------------
__global__ void vq_stats(const float* __restrict__ counts,
                         const float* __restrict__ cs_in1,
                         const float* __restrict__ cs_in2,
                         float* __restrict__ cs_final,
                         float* __restrict__ out) {
    __shared__ float red[512];
    const int k = threadIdx.x;   // 512 threads
    float perp_tot = 0.f;
    for (int h = 0; h < 2; ++h) {
        const float* csin = h ? cs_in2 : cs_in1;
        float cnt = counts[(h << 9) + k];
        float csn = DECAYF * csin[k] + OMDF * cnt;
        red[k] = csn;
        __syncthreads();
        for (int s = 256; s > 0; s >>= 1) {
            if (k < s) red[k] += red[k + s];
            __syncthreads();
        }
        float n = red[0];
        __syncthreads();
        cs_final[(h << 9) + k] = (csn + EPSF) / (n + 512.0f * EPSF) * n;
        float p = cnt * (1.0f / 65536.0f);
        float e = p * logf(p + 1e-10f);
        red[k] = e;
        __syncthreads();
        for (int s = 256; s > 0; s >>= 1) {
            if (k < s) red[k] += red[k + s];
            __syncthreads();
        }
        if (k == 0) perp_tot += expf(-red[0]);
        __syncthreads();
    }
    if (k == 0) out[33554433] = perp_tot;
}

// ---------------- kernel D2: new_emb = (decay*ema_w + 0.01*dw) / cs ----------------
__global__ __launch_bounds__(256) void vq_newemb(const float* __restrict__ dw,
                                                 const float* __restrict__ w1,
                                                 const float* __restrict__ w2,
                                                 const float* __restrict__ cs_final,
                                                 float* __restrict__ new_emb) {
    int g = blockIdx.x * 256 + threadIdx.x;  // float4 index 0..65535
    int h = g >> 15;
    int k = (g >> 6) & 511;
    const float* wi = h ? w2 : w1;
    float4 d4 = *reinterpret_cast<const float4*>(dw + (size_t)g * 4);
    float4 w4 = *reinterpret_cast<const float4*>(wi + (size_t)(g & 32767) * 4);
    float cs = cs_final[(h << 9) + k];
    float4 o;
    o.x = (DECAYF * w4.x + OMDF * d4.x) / cs;
    o.y = (DECAYF * w4.y + OMDF * d4.y) / cs;
    o.z = (DECAYF * w4.z + OMDF * d4.z) / cs;
    o.w = (DECAYF * w4.w + OMDF * d4.w) / cs;
    *reinterpret_cast<float4*>(new_emb + (size_t)g * 4) = o;
}

// ---------------- kernel E: gather + transpose-out + vq_loss ----------------
__global__ __launch_bounds__(256) void vq_out(const float* __restrict__ x,
                                              const float* __restrict__ new_emb,
                                              const int* __restrict__ idx,
                                              float* __restrict__ out) {
    __shared__ int idx_l[2][64];
    __shared__ float wsum[4];
    const int tid = threadIdx.x;
    const int b = blockIdx.x >> 5;
    const int t0 = (blockIdx.x & 31) << 6;
    if (tid < 128) {
        int h = tid >> 6, t = tid & 63;
        idx_l[h][t] = idx[h * NROWS + b * TT + t0 + t];
    }
    __syncthreads();
    const int lane = tid & 63;
    const int w = tid >> 6;
    const size_t xb = (size_t)b * BD * TT + t0 + lane;
    float lsum = 0.f;
    for (int i = 0; i < 128; ++i) {
        int c = i * 4 + w;
        int h = c >> 8, cp = c & 255;
        int k = idx_l[h][lane];
        float q = new_emb[(size_t)((h << 9) + k) * SUBD + cp];
        float xv = x[xb + (size_t)c * TT];
        float t1 = q - xv;          // stop_gradient(quant - xt)
        float o = xv + t1;          // quant_st, matching reference rounding
        out[xb + (size_t)c * TT] = o;
        lsum += t1 * t1;
    }
#pragma unroll
    for (int m = 1; m < 64; m <<= 1) lsum += __shfl_xor(lsum, m);
    if (lane == 0) wsum[w] = lsum;
    __syncthreads();
    if (tid == 0) {
        float s = wsum[0] + wsum[1] + wsum[2] + wsum[3];
        atomicAdd(out + 33554432, s * (0.25f / 33554432.0f));
    }
}

extern "C" void kernel_launch(void* const* d_in, const int* in_sizes, int n_in,
                              void* d_out, int out_size, void* d_ws, size_t ws_size,
                              hipStream_t stream) {
    const float* x    = (const float*)d_in[0];
    const float* emb1 = (const float*)d_in[1];
    const float* emb2 = (const float*)d_in[2];
    const float* cs1  = (const float*)d_in[3];
    const float* w1   = (const float*)d_in[4];
    const float* cs2  = (const float*)d_in[5];
    const float* w2   = (const float*)d_in[6];
    float* out = (float*)d_out;
    float* ws  = (float*)d_ws;

    float* counts = ws;                 // 1024 floats
    float* dw     = ws + 1024;          // 262144 floats
    float* csf    = ws + 263168;        // 1024
    float* se2    = ws + 264192;        // 1024
    float* nemb   = ws + 265216;        // 262144
    int*   idx    = (int*)(ws + 527360);// 131072 ints

    // zero the accumulators (counts + dw are contiguous)
    hipMemsetAsync(counts, 0, (1024 + 262144) * sizeof(float), stream);
    hipMemsetAsync(out + 33554432, 0, 2 * sizeof(float), stream);

    vq_sume2 <<<4,    256, 0, stream>>>(emb1, emb2, se2);
    vq_argmin<<<1024, 256, 0, stream>>>(x, emb1, emb2, se2, counts, dw, idx);
    vq_stats <<<1,    512, 0, stream>>>(counts, cs1, cs2, csf, out);
    vq_newemb<<<256,  256, 0, stream>>>(dw, w1, w2, csf, nemb);
    vq_out   <<<1024, 256, 0, stream>>>(x, nemb, idx, out);
}

// Round 2
// 1639.870 us; speedup vs baseline: 1.3470x; 1.3470x over previous
//
#include <hip/hip_runtime.h>

#define NK 512
#define SUBD 256
#define TT 2048
#define BD 512
#define NROWS 65536
#define DECAYF 0.99f
#define OMDF 0.01f
#define EPSF 1e-5f
#define FLT_BIG 3.402823466e+38f

// ---------------- kernel P0: sume2[h][k] = sum_c emb[k][c]^2 ----------------
__global__ __launch_bounds__(256) void vq_sume2(const float* __restrict__ emb1,
                                                const float* __restrict__ emb2,
                                                float* __restrict__ sume2) {
    int r = blockIdx.x * 256 + threadIdx.x;   // 0..1023
    const float* e = (r >> 9) ? emb2 : emb1;
    const float* row = e + (size_t)(r & 511) * SUBD;
    float s = 0.f;
#pragma unroll 8
    for (int i = 0; i < 64; ++i) {
        float4 v = *reinterpret_cast<const float4*>(row + i * 4);
        s += v.x * v.x + v.y * v.y + v.z * v.z + v.w * v.w;
    }
    sume2[r] = s;
}

// ---------------- kernel A: argmin + counts (x-in-registers GEMM) ----------------
// grid 512; block 256 = 4 waves; wave owns 32 rows, lane L and L^32 pair on one
// row (L<32: c[0:128), L>=32: c[128:256) of the half). emb streamed via LDS
// double-buffered 32k x 256c tiles; T14 split staging (load early, ds_write late).
__global__ __launch_bounds__(256, 2) void vq_argmin2(const float* __restrict__ x,
                                                     const float* __restrict__ emb1,
                                                     const float* __restrict__ emb2,
                                                     const float* __restrict__ sume2,
                                                     float* __restrict__ counts,
                                                     int* __restrict__ idx_out) {
    __shared__ float eb[2][32 * 256];   // 64 KB double-buffered emb tile [kk][c]
    __shared__ float se_l[512];

    const int tid = threadIdx.x;
    const int lane = tid & 63;
    const int w = tid >> 6;
    const int r = blockIdx.x * 128 + w * 32 + (lane & 31);
    const int bb = r >> 11;
    const int t = r & 2047;
    const int ch = (lane >> 5) << 7;    // 0 or 128 (c-half within the 256)

    float4 xr[32];                      // my 128 channels, statically indexed

    for (int h = 0; h < 2; ++h) {
        const float* embp = h ? emb2 : emb1;

        // ---- load my 128 channels of row r (coalesced along t across lanes) ----
        const float* xb = x + ((size_t)bb * BD + (h << 8) + ch) * TT + t;
#pragma unroll
        for (int c4 = 0; c4 < 32; ++c4) {
            xr[c4].x = xb[(size_t)(c4 * 4 + 0) * TT];
            xr[c4].y = xb[(size_t)(c4 * 4 + 1) * TT];
            xr[c4].z = xb[(size_t)(c4 * 4 + 2) * TT];
            xr[c4].w = xb[(size_t)(c4 * 4 + 3) * TT];
        }
        float s = 0.f;
#pragma unroll
        for (int c4 = 0; c4 < 32; ++c4)
            s += xr[c4].x * xr[c4].x + xr[c4].y * xr[c4].y +
                 xr[c4].z * xr[c4].z + xr[c4].w * xr[c4].w;
        const float f2 = s + __shfl_xor(s, 32);

        // ---- stage se2 + emb tile 0 ----
        se_l[tid]       = sume2[(h << 9) + tid];
        se_l[tid + 256] = sume2[(h << 9) + 256 + tid];
        {
            float4 st[8];
#pragma unroll
            for (int p = 0; p < 8; ++p) {
                int j = tid + p * 256;
                st[p] = *reinterpret_cast<const float4*>(
                    embp + (size_t)(j >> 6) * SUBD + (j & 63) * 4);
            }
#pragma unroll
            for (int p = 0; p < 8; ++p)
                *reinterpret_cast<float4*>(&eb[0][(tid + p * 256) * 4]) = st[p];
        }
        __syncthreads();

        float bd = FLT_BIG;
        int bk = 0;
        int buf = 0;
        for (int kt = 0; kt < 16; ++kt) {
            // issue next tile's loads early (hide HBM/L2 latency under compute)
            float4 st[8];
            const bool pf = (kt < 15);
            if (pf) {
                const float* esrc = embp + (size_t)(kt + 1) * 32 * SUBD;
#pragma unroll
                for (int p = 0; p < 8; ++p) {
                    int j = tid + p * 256;
                    st[p] = *reinterpret_cast<const float4*>(
                        esrc + (size_t)(j >> 6) * SUBD + (j & 63) * 4);
                }
            }
            const float* ebp_ = &eb[buf][0];
            const int k0 = kt << 5;
            for (int g = 0; g < 8; ++g) {     // 4 k's per group, fresh accumulators
                const float* ebg = ebp_ + (g << 10) + ch;
                float a0 = 0.f, a1 = 0.f, a2 = 0.f, a3 = 0.f;
#pragma unroll
                for (int c4 = 0; c4 < 32; ++c4) {
                    const float4 xv = xr[c4];
                    const float4 e0 = *reinterpret_cast<const float4*>(ebg + 0 * 256 + c4 * 4);
                    const float4 e1 = *reinterpret_cast<const float4*>(ebg + 1 * 256 + c4 * 4);
                    const float4 e2 = *reinterpret_cast<const float4*>(ebg + 2 * 256 + c4 * 4);
                    const float4 e3 = *reinterpret_cast<const float4*>(ebg + 3 * 256 + c4 * 4);
                    a0 += xv.x * e0.x; a0 += xv.y * e0.y; a0 += xv.z * e0.z; a0 += xv.w * e0.w;
                    a1 += xv.x * e1.x; a1 += xv.y * e1.y; a1 += xv.z * e1.z; a1 += xv.w * e1.w;
                    a2 += xv.x * e2.x; a2 += xv.y * e2.y; a2 += xv.z * e2.z; a2 += xv.w * e2.w;
                    a3 += xv.x * e3.x; a3 += xv.y * e3.y; a3 += xv.z * e3.z; a3 += xv.w * e3.w;
                }
                const float d0 = a0 + __shfl_xor(a0, 32);
                const float d1 = a1 + __shfl_xor(a1, 32);
                const float d2 = a2 + __shfl_xor(a2, 32);
                const float d3 = a3 + __shfl_xor(a3, 32);
                const int kb = k0 + (g << 2);
                float d;
                d = (f2 + se_l[kb + 0]) - 2.0f * d0; if (d < bd) { bd = d; bk = kb + 0; }
                d = (f2 + se_l[kb + 1]) - 2.0f * d1; if (d < bd) { bd = d; bk = kb + 1; }
                d = (f2 + se_l[kb + 2]) - 2.0f * d2; if (d < bd) { bd = d; bk = kb + 2; }
                d = (f2 + se_l[kb + 3]) - 2.0f * d3; if (d < bd) { bd = d; bk = kb + 3; }
            }
            if (pf) {
                float* ebn = &eb[buf ^ 1][0];
#pragma unroll
                for (int p = 0; p < 8; ++p)
                    *reinterpret_cast<float4*>(&ebn[(tid + p * 256) * 4]) = st[p];
            }
            __syncthreads();
            buf ^= 1;
        }
        if (lane < 32) {
            idx_out[(h << 16) + r] = bk;
            atomicAdd(&counts[(h << 9) + bk], 1.0f);
        }
        __syncthreads();
    }
}

// ---------------- kernel B: dw via LDS-privatized histogram ----------------
// grid 64 = 2 h x 4 c-ranges x 8 row-slabs; 128 KB LDS partial [64 c][512 k]
__global__ __launch_bounds__(256) void vq_dw(const float* __restrict__ x,
                                             const int* __restrict__ idx,
                                             float* __restrict__ dw) {
    __shared__ float dwp[64 * 512];
    const int tid = threadIdx.x;
    const int h = blockIdx.x & 1;
    const int cr = (blockIdx.x >> 1) & 3;
    const int slab = blockIdx.x >> 3;   // 0..7, 8192 rows each
#pragma unroll 8
    for (int i = 0; i < 128; ++i) dwp[tid + i * 256] = 0.f;
    __syncthreads();
    for (int it = 0; it < 32; ++it) {
        const int r = (slab << 13) + (it << 8) + tid;
        const int k = idx[(h << 16) + r];
        const int bb = r >> 11;
        const int t = r & 2047;
        const float* xb = x + ((size_t)bb * BD + (h << 8) + (cr << 6)) * TT + t;
#pragma unroll
        for (int c = 0; c < 64; ++c)
            atomicAdd(&dwp[(c << 9) + k], xb[(size_t)c * TT]);
    }
    __syncthreads();
#pragma unroll 8
    for (int i = 0; i < 128; ++i) {
        const int j = tid + i * 256;
        const int k = j & 511;
        const int c = j >> 9;
        atomicAdd(&dw[((h << 9) + k) * SUBD + (cr << 6) + c], dwp[j]);
    }
}

// ---------------- kernel D1: EMA cluster-size smoothing + perplexity ----------------
__global__ void vq_stats(const float* __restrict__ counts,
                         const float* __restrict__ cs_in1,
                         const float* __restrict__ cs_in2,
                         float* __restrict__ cs_final,
                         float* __restrict__ out) {
    __shared__ float red[512];
    const int k = threadIdx.x;   // 512 threads
    float perp_tot = 0.f;
    for (int h = 0; h < 2; ++h) {
        const float* csin = h ? cs_in2 : cs_in1;
        float cnt = counts[(h << 9) + k];
        float csn = DECAYF * csin[k] + OMDF * cnt;
        red[k] = csn;
        __syncthreads();
        for (int s = 256; s > 0; s >>= 1) {
            if (k < s) red[k] += red[k + s];
            __syncthreads();
        }
        float n = red[0];
        __syncthreads();
        cs_final[(h << 9) + k] = (csn + EPSF) / (n + 512.0f * EPSF) * n;
        float p = cnt * (1.0f / 65536.0f);
        float e = p * logf(p + 1e-10f);
        red[k] = e;
        __syncthreads();
        for (int s = 256; s > 0; s >>= 1) {
            if (k < s) red[k] += red[k + s];
            __syncthreads();
        }
        if (k == 0) perp_tot += expf(-red[0]);
        __syncthreads();
    }
    if (k == 0) out[33554433] = perp_tot;
}

// ---------------- kernel D2: new_emb = (decay*ema_w + 0.01*dw) / cs ----------------
__global__ __launch_bounds__(256) void vq_newemb(const float* __restrict__ dw,
                                                 const float* __restrict__ w1,
                                                 const float* __restrict__ w2,
                                                 const float* __restrict__ cs_final,
                                                 float* __restrict__ new_emb) {
    int g = blockIdx.x * 256 + threadIdx.x;  // float4 index 0..65535
    int h = g >> 15;
    int k = (g >> 6) & 511;
    const float* wi = h ? w2 : w1;
    float4 d4 = *reinterpret_cast<const float4*>(dw + (size_t)g * 4);
    float4 w4 = *reinterpret_cast<const float4*>(wi + (size_t)(g & 32767) * 4);
    float cs = cs_final[(h << 9) + k];
    float4 o;
    o.x = (DECAYF * w4.x + OMDF * d4.x) / cs;
    o.y = (DECAYF * w4.y + OMDF * d4.y) / cs;
    o.z = (DECAYF * w4.z + OMDF * d4.z) / cs;
    o.w = (DECAYF * w4.w + OMDF * d4.w) / cs;
    *reinterpret_cast<float4*>(new_emb + (size_t)g * 4) = o;
}

// ---------------- kernel E: gather + transpose-out + vq_loss ----------------
__global__ __launch_bounds__(256) void vq_out(const float* __restrict__ x,
                                              const float* __restrict__ new_emb,
                                              const int* __restrict__ idx,
                                              float* __restrict__ out) {
    __shared__ int idx_l[2][64];
    __shared__ float wsum[4];
    const int tid = threadIdx.x;
    const int b = blockIdx.x >> 5;
    const int t0 = (blockIdx.x & 31) << 6;
    if (tid < 128) {
        int h = tid >> 6, t = tid & 63;
        idx_l[h][t] = idx[h * NROWS + b * TT + t0 + t];
    }
    __syncthreads();
    const int lane = tid & 63;
    const int w = tid >> 6;
    const size_t xb = (size_t)b * BD * TT + t0 + lane;
    float lsum = 0.f;
    for (int i = 0; i < 128; ++i) {
        int c = i * 4 + w;
        int h = c >> 8, cp = c & 255;
        int k = idx_l[h][lane];
        float q = new_emb[(size_t)((h << 9) + k) * SUBD + cp];
        float xv = x[xb + (size_t)c * TT];
        float t1 = q - xv;          // stop_gradient(quant - xt)
        float o = xv + t1;          // quant_st, matching reference rounding
        out[xb + (size_t)c * TT] = o;
        lsum += t1 * t1;
    }
#pragma unroll
    for (int m = 1; m < 64; m <<= 1) lsum += __shfl_xor(lsum, m);
    if (lane == 0) wsum[w] = lsum;
    __syncthreads();
    if (tid == 0) {
        float s = wsum[0] + wsum[1] + wsum[2] + wsum[3];
        atomicAdd(out + 33554432, s * (0.25f / 33554432.0f));
    }
}

extern "C" void kernel_launch(void* const* d_in, const int* in_sizes, int n_in,
                              void* d_out, int out_size, void* d_ws, size_t ws_size,
                              hipStream_t stream) {
    const float* x    = (const float*)d_in[0];
    const float* emb1 = (const float*)d_in[1];
    const float* emb2 = (const float*)d_in[2];
    const float* cs1  = (const float*)d_in[3];
    const float* w1   = (const float*)d_in[4];
    const float* cs2  = (const float*)d_in[5];
    const float* w2   = (const float*)d_in[6];
    float* out = (float*)d_out;
    float* ws  = (float*)d_ws;

    float* counts = ws;                 // 1024 floats
    float* dw     = ws + 1024;          // 262144 floats
    float* csf    = ws + 263168;        // 1024
    float* se2    = ws + 264192;        // 1024
    float* nemb   = ws + 265216;        // 262144
    int*   idx    = (int*)(ws + 527360);// 131072 ints

    // zero the accumulators (counts + dw are contiguous)
    hipMemsetAsync(counts, 0, (1024 + 262144) * sizeof(float), stream);
    hipMemsetAsync(out + 33554432, 0, 2 * sizeof(float), stream);

    vq_sume2  <<<4,    256, 0, stream>>>(emb1, emb2, se2);
    vq_argmin2<<<512,  256, 0, stream>>>(x, emb1, emb2, se2, counts, idx);
    vq_dw     <<<64,   256, 0, stream>>>(x, idx, dw);
    vq_stats  <<<1,    512, 0, stream>>>(counts, cs1, cs2, csf, out);
    vq_newemb <<<256,  256, 0, stream>>>(dw, w1, w2, csf, nemb);
    vq_out    <<<1024, 256, 0, stream>>>(x, nemb, idx, out);
}

// Round 3
// 799.736 us; speedup vs baseline: 2.7621x; 2.0505x over previous
//
#include <hip/hip_runtime.h>

typedef short short8 __attribute__((ext_vector_type(8)));
typedef float f32x4 __attribute__((ext_vector_type(4)));

#define NK 512
#define SUBD 256
#define TT 2048
#define BD 512
#define NROWS 65536
#define DECAYF 0.99f
#define OMDF 0.01f
#define EPSF 1e-5f
#define FLT_BIG 3.402823466e+38f

static __device__ __forceinline__ ushort f2bf(float f) {
    uint u = __float_as_uint(f);
    u += 0x7FFFu + ((u >> 16) & 1u);
    return (ushort)(u >> 16);
}
static __device__ __forceinline__ float bf2f(ushort h) {
    return __uint_as_float(((uint)h) << 16);
}
union UCast { uint4 u; short8 s; };
static __device__ __forceinline__ short8 as_s8(uint4 v) { UCast c; c.u = v; return c.s; }

// ---------------- P0: sume2[h][k] = sum_c emb[k][c]^2 (exact fp32) ----------------
__global__ __launch_bounds__(256) void vq_sume2(const float* __restrict__ emb1,
                                                const float* __restrict__ emb2,
                                                float* __restrict__ sume2) {
    int r = blockIdx.x * 256 + threadIdx.x;
    const float* e = (r >> 9) ? emb2 : emb1;
    const float* row = e + (size_t)(r & 511) * SUBD;
    float s = 0.f;
#pragma unroll 8
    for (int i = 0; i < 64; ++i) {
        float4 v = *reinterpret_cast<const float4*>(row + i * 4);
        s += v.x * v.x + v.y * v.y + v.z * v.z + v.w * v.w;
    }
    sume2[r] = s;
}

// ---------------- P1: pre-convert emb to split-bf16, pre-swizzled staged layout ----
// embst[h][stage s=kh*8+cs][spl][k 0..255][gp 0..3] (uint4 = 8 bf16)
__global__ __launch_bounds__(256) void vq_embcvt(const float* __restrict__ emb1,
                                                 const float* __restrict__ emb2,
                                                 uint4* __restrict__ embst) {
    int id = blockIdx.x * 256 + threadIdx.x;      // 0..65535
    int h   = id >> 15;
    int s   = (id >> 11) & 15;
    int spl = (id >> 10) & 1;
    int k   = (id >> 2) & 255;
    int gp  = id & 3;
    int kh = s >> 3, cs = s & 7;
    int gl = gp ^ (k & 3);                        // un-swizzle to logical c-group
    const float* e = h ? emb2 : emb1;
    const float* src = e + (size_t)(kh * 256 + k) * SUBD + cs * 32 + gl * 8;
    float4 v0 = *reinterpret_cast<const float4*>(src);
    float4 v1 = *reinterpret_cast<const float4*>(src + 4);
    float f[8] = {v0.x, v0.y, v0.z, v0.w, v1.x, v1.y, v1.z, v1.w};
    ushort o[8];
#pragma unroll
    for (int i = 0; i < 8; ++i) {
        ushort hh = f2bf(f[i]);
        o[i] = spl ? f2bf(f[i] - bf2f(hh)) : hh;
    }
    uint4 d;
    d.x = o[0] | ((uint)o[1] << 16);
    d.y = o[2] | ((uint)o[3] << 16);
    d.z = o[4] | ((uint)o[5] << 16);
    d.w = o[6] | ((uint)o[7] << 16);
    embst[id] = d;
}

// ---------------- A: argmin via split-bf16 MFMA ----------------
// grid 2048 = 1024 r-blocks (64 rows) x 2 halves; 512 threads = 8 waves (2 wr x 4 wk)
// wave tile 32r x 64k, mfma_f32_16x16x32_bf16, 3 products (hi*hi + hi*lo + lo*hi)
__global__ __launch_bounds__(512) void vq_argmin3(const float* __restrict__ x,
                                                  const uint4* __restrict__ embst,
                                                  const float* __restrict__ sume2,
                                                  float* __restrict__ counts,
                                                  int* __restrict__ idx_out) {
    __shared__ uint4 Ah[64 * 32];     // 32 KB  x_hi, XOR-swizzled 16B groups
    __shared__ uint4 Al[64 * 32];     // 32 KB  x_lo
    __shared__ uint4 Bb[2][2048];     // 64 KB  emb tile dbuf [buf][spl*1024 + k*4 + gp]
    __shared__ float f2s[64];
    __shared__ float se_l[512];
    __shared__ float wbd[4][64];
    __shared__ int   wbk[4][64];

    const int tid = threadIdx.x;
    const int bid = blockIdx.x;
    const int h  = bid & 1;
    const int rb = bid >> 1;            // 0..1023
    const int b  = rb >> 5;
    const int t0 = (rb & 31) << 6;      // 64 rows

    // ---- init tables ----
    if (tid < 64) f2s[tid] = 0.f;
    se_l[tid & 511] = sume2[h * NK + (tid & 511)];
    __syncthreads();

    // ---- stage A: transpose x -> LDS as bf16 hi/lo, swizzled ----
    {
        const int r  = tid & 63;
        const int cq = tid >> 6;        // 0..7
        const float* xb = x + ((size_t)b * BD + h * 256) * TT + t0 + r;
        float f2p = 0.f;
#pragma unroll
        for (int it = 0; it < 4; ++it) {
            const int c0 = cq * 32 + it * 8;
            float v[8];
#pragma unroll
            for (int j = 0; j < 8; ++j) v[j] = xb[(size_t)(c0 + j) * TT];
            ushort hi[8], lo[8];
#pragma unroll
            for (int j = 0; j < 8; ++j) {
                hi[j] = f2bf(v[j]);
                lo[j] = f2bf(v[j] - bf2f(hi[j]));
                f2p += v[j] * v[j];
            }
            uint4 uh, ul;
            uh.x = hi[0] | ((uint)hi[1] << 16); uh.y = hi[2] | ((uint)hi[3] << 16);
            uh.z = hi[4] | ((uint)hi[5] << 16); uh.w = hi[6] | ((uint)hi[7] << 16);
            ul.x = lo[0] | ((uint)lo[1] << 16); ul.y = lo[2] | ((uint)lo[3] << 16);
            ul.z = lo[4] | ((uint)lo[5] << 16); ul.w = lo[6] | ((uint)lo[7] << 16);
            const int phys = (c0 >> 3) ^ (r & 7);
            Ah[r * 32 + phys] = uh;
            Al[r * 32 + phys] = ul;
        }
        atomicAdd(&f2s[r], f2p);
    }

    // ---- stage B tile 0 ----
    {
        const uint4* src = embst + (size_t)h * 32768;
#pragma unroll
        for (int i = 0; i < 4; ++i) Bb[0][tid + i * 512] = src[tid + i * 512];
    }
    __syncthreads();

    const int l   = tid & 63;
    const int w   = tid >> 6;
    const int wr  = w >> 2, wk = w & 3;
    const int l15 = l & 15, l4 = l >> 4;
    const int bBase = l15 * 4 + (l4 ^ (l & 3));   // B lane offset (+wk*256 +kg*64 +spl*1024)

    float bd8[8]; int bk8[8];
#pragma unroll
    for (int i = 0; i < 8; ++i) { bd8[i] = FLT_BIG; bk8[i] = 0; }

    int buf = 0;
    for (int kh = 0; kh < 2; ++kh) {
        f32x4 acc[2][4];
#pragma unroll
        for (int rg = 0; rg < 2; ++rg)
#pragma unroll
            for (int kg = 0; kg < 4; ++kg) acc[rg][kg] = (f32x4)0.f;

        for (int cs = 0; cs < 8; ++cs) {
            const int s = kh * 8 + cs;
            uint4 st[4];
            const bool pf = (s < 15);
            if (pf) {
                const uint4* src = embst + (size_t)h * 32768 + (size_t)(s + 1) * 2048;
#pragma unroll
                for (int i = 0; i < 4; ++i) st[i] = src[tid + i * 512];
            }
            short8 ah[2], al[2];
#pragma unroll
            for (int rg = 0; rg < 2; ++rg) {
                const int row = wr * 32 + rg * 16 + l15;
                const int ia = row * 32 + ((cs * 4 + l4) ^ (row & 7));
                ah[rg] = as_s8(Ah[ia]);
                al[rg] = as_s8(Al[ia]);
            }
            short8 bh[4], bl[4];
#pragma unroll
            for (int kg = 0; kg < 4; ++kg) {
                const int ib = wk * 256 + kg * 64 + bBase;
                bh[kg] = as_s8(Bb[buf][ib]);
                bl[kg] = as_s8(Bb[buf][1024 + ib]);
            }
#pragma unroll
            for (int rg = 0; rg < 2; ++rg)
#pragma unroll
                for (int kg = 0; kg < 4; ++kg) {
                    acc[rg][kg] = __builtin_amdgcn_mfma_f32_16x16x32_bf16(ah[rg], bh[kg], acc[rg][kg], 0, 0, 0);
                    acc[rg][kg] = __builtin_amdgcn_mfma_f32_16x16x32_bf16(ah[rg], bl[kg], acc[rg][kg], 0, 0, 0);
                    acc[rg][kg] = __builtin_amdgcn_mfma_f32_16x16x32_bf16(al[rg], bh[kg], acc[rg][kg], 0, 0, 0);
                }
            if (pf) {
#pragma unroll
                for (int i = 0; i < 4; ++i) Bb[buf ^ 1][tid + i * 512] = st[i];
            }
            __syncthreads();
            buf ^= 1;
        }
        // ---- lane-local argmin update (k ascending -> strict < = min-k tie-break) ----
#pragma unroll
        for (int rg = 0; rg < 2; ++rg)
#pragma unroll
            for (int kg = 0; kg < 4; ++kg) {
                const int k = kh * 256 + wk * 64 + kg * 16 + l15;
                const float se = se_l[k];
#pragma unroll
                for (int reg = 0; reg < 4; ++reg) {
                    const int row = wr * 32 + rg * 16 + l4 * 4 + reg;
                    const float d = (f2s[row] + se) - 2.0f * acc[rg][kg][reg];
                    const int i8 = rg * 4 + reg;
                    if (d < bd8[i8]) { bd8[i8] = d; bk8[i8] = k; }
                }
            }
    }

    // ---- reduce across the 16 k-lanes ----
#pragma unroll
    for (int m = 1; m < 16; m <<= 1) {
#pragma unroll
        for (int i = 0; i < 8; ++i) {
            const float od = __shfl_xor(bd8[i], m);
            const int   ok = __shfl_xor(bk8[i], m);
            if (od < bd8[i] || (od == bd8[i] && ok < bk8[i])) { bd8[i] = od; bk8[i] = ok; }
        }
    }
    if (l15 == 0) {
#pragma unroll
        for (int i = 0; i < 8; ++i) {
            const int rg = i >> 2, reg = i & 3;
            const int rr = wr * 32 + rg * 16 + l4 * 4 + reg;
            wbd[wk][rr] = bd8[i]; wbk[wk][rr] = bk8[i];
        }
    }
    __syncthreads();
    if (tid < 64) {
        float bd = wbd[0][tid]; int bk = wbk[0][tid];
#pragma unroll
        for (int q = 1; q < 4; ++q) {
            const float od = wbd[q][tid]; const int ok = wbk[q][tid];
            if (od < bd || (od == bd && ok < bk)) { bd = od; bk = ok; }
        }
        const int rglob = b * TT + t0 + tid;
        idx_out[h * NROWS + rglob] = bk;
        atomicAdd(&counts[(h << 9) + bk], 1.0f);
    }
}

// ---------------- B: dw via LDS-privatized histogram ----------------
// grid 128 = 2h x 4cr(64c) x 16 slabs(4096 rows); LDS [64c][512k]
__global__ __launch_bounds__(256) void vq_dw(const float* __restrict__ x,
                                             const int* __restrict__ idx,
                                             float* __restrict__ dw) {
    __shared__ float dwp[64 * 512];
    const int tid = threadIdx.x;
    const int h = blockIdx.x & 1;
    const int cr = (blockIdx.x >> 1) & 3;
    const int slab = blockIdx.x >> 3;   // 0..15
#pragma unroll 8
    for (int i = 0; i < 128; ++i) dwp[tid + i * 256] = 0.f;
    __syncthreads();
    for (int it = 0; it < 16; ++it) {
        const int r = (slab << 12) + (it << 8) + tid;
        const int k = idx[(h << 16) + r];
        const float* xb = x + ((size_t)(r >> 11) * BD + (h << 8) + (cr << 6)) * TT + (r & 2047);
#pragma unroll
        for (int c = 0; c < 64; ++c)
            atomicAdd(&dwp[(c << 9) + k], xb[(size_t)c * TT]);
    }
    __syncthreads();
#pragma unroll 8
    for (int i = 0; i < 128; ++i) {
        const int j = tid + i * 256;
        const int k = j & 511;
        const int c = j >> 9;
        atomicAdd(&dw[(size_t)((h << 9) + k) * SUBD + (cr << 6) + c], dwp[j]);
    }
}

// ---------------- D1: EMA cluster-size smoothing + perplexity ----------------
__global__ void vq_stats(const float* __restrict__ counts,
                         const float* __restrict__ cs_in1,
                         const float* __restrict__ cs_in2,
                         float* __restrict__ cs_final,
                         float* __restrict__ out) {
    __shared__ float red[512];
    const int k = threadIdx.x;
    float perp_tot = 0.f;
    for (int h = 0; h < 2; ++h) {
        const float* csin = h ? cs_in2 : cs_in1;
        float cnt = counts[(h << 9) + k];
        float csn = DECAYF * csin[k] + OMDF * cnt;
        red[k] = csn;
        __syncthreads();
        for (int s = 256; s > 0; s >>= 1) {
            if (k < s) red[k] += red[k + s];
            __syncthreads();
        }
        float n = red[0];
        __syncthreads();
        cs_final[(h << 9) + k] = (csn + EPSF) / (n + 512.0f * EPSF) * n;
        float p = cnt * (1.0f / 65536.0f);
        float e = p * logf(p + 1e-10f);
        red[k] = e;
        __syncthreads();
        for (int s = 256; s > 0; s >>= 1) {
            if (k < s) red[k] += red[k + s];
            __syncthreads();
        }
        if (k == 0) perp_tot += expf(-red[0]);
        __syncthreads();
    }
    if (k == 0) out[33554433] = perp_tot;
}

// ---------------- D2: new_emb = (decay*ema_w + 0.01*dw) / cs ----------------
__global__ __launch_bounds__(256) void vq_newemb(const float* __restrict__ dw,
                                                 const float* __restrict__ w1,
                                                 const float* __restrict__ w2,
                                                 const float* __restrict__ cs_final,
                                                 float* __restrict__ new_emb) {
    int g = blockIdx.x * 256 + threadIdx.x;
    int h = g >> 15;
    int k = (g >> 6) & 511;
    const float* wi = h ? w2 : w1;
    float4 d4 = *reinterpret_cast<const float4*>(dw + (size_t)g * 4);
    float4 w4 = *reinterpret_cast<const float4*>(wi + (size_t)(g & 32767) * 4);
    float cs = cs_final[(h << 9) + k];
    float4 o;
    o.x = (DECAYF * w4.x + OMDF * d4.x) / cs;
    o.y = (DECAYF * w4.y + OMDF * d4.y) / cs;
    o.z = (DECAYF * w4.z + OMDF * d4.z) / cs;
    o.w = (DECAYF * w4.w + OMDF * d4.w) / cs;
    *reinterpret_cast<float4*>(new_emb + (size_t)g * 4) = o;
}

// ---------------- E: gather + output + vq_loss (float4 on the big stream) --------
__global__ __launch_bounds__(256) void vq_out(const float* __restrict__ x,
                                              const float* __restrict__ nemb,
                                              const int* __restrict__ idx,
                                              float* __restrict__ out) {
    __shared__ int idx_l[2][64];
    __shared__ float wsum[4];
    const int tid = threadIdx.x;
    const int b = blockIdx.x >> 5;
    const int t0 = (blockIdx.x & 31) << 6;
    if (tid < 128) {
        int hh = tid >> 6, t = tid & 63;
        idx_l[hh][t] = idx[hh * NROWS + b * TT + t0 + t];
    }
    __syncthreads();
    const int tq = tid & 15;
    const int cw = tid >> 4;
    const int k0 = idx_l[0][tq * 4 + 0], k1 = idx_l[0][tq * 4 + 1];
    const int k2 = idx_l[0][tq * 4 + 2], k3 = idx_l[0][tq * 4 + 3];
    const int m0 = idx_l[1][tq * 4 + 0], m1 = idx_l[1][tq * 4 + 1];
    const int m2 = idx_l[1][tq * 4 + 2], m3 = idx_l[1][tq * 4 + 3];
    float lsum = 0.f;
    for (int i = 0; i < 32; ++i) {
        const int c = cw + i * 16;
        const int hh = c >> 8, cp = c & 255;
        const size_t base = ((size_t)b * BD + c) * TT + t0 + tq * 4;
        float4 xv = *reinterpret_cast<const float4*>(x + base);
        const size_t eb = (size_t)(hh << 9) * SUBD + cp;
        float q0 = nemb[eb + (size_t)(hh ? m0 : k0) * SUBD];
        float q1 = nemb[eb + (size_t)(hh ? m1 : k1) * SUBD];
        float q2 = nemb[eb + (size_t)(hh ? m2 : k2) * SUBD];
        float q3 = nemb[eb + (size_t)(hh ? m3 : k3) * SUBD];
        float4 o; float t1;
        t1 = q0 - xv.x; o.x = xv.x + t1; lsum += t1 * t1;
        t1 = q1 - xv.y; o.y = xv.y + t1; lsum += t1 * t1;
        t1 = q2 - xv.z; o.z = xv.z + t1; lsum += t1 * t1;
        t1 = q3 - xv.w; o.w = xv.w + t1; lsum += t1 * t1;
        *reinterpret_cast<float4*>(out + base) = o;
    }
#pragma unroll
    for (int m = 1; m < 64; m <<= 1) lsum += __shfl_xor(lsum, m);
    if ((tid & 63) == 0) wsum[tid >> 6] = lsum;
    __syncthreads();
    if (tid == 0) {
        float s = wsum[0] + wsum[1] + wsum[2] + wsum[3];
        atomicAdd(out + 33554432, s * (0.25f / 33554432.0f));
    }
}

extern "C" void kernel_launch(void* const* d_in, const int* in_sizes, int n_in,
                              void* d_out, int out_size, void* d_ws, size_t ws_size,
                              hipStream_t stream) {
    const float* x    = (const float*)d_in[0];
    const float* emb1 = (const float*)d_in[1];
    const float* emb2 = (const float*)d_in[2];
    const float* cs1  = (const float*)d_in[3];
    const float* w1   = (const float*)d_in[4];
    const float* cs2  = (const float*)d_in[5];
    const float* w2   = (const float*)d_in[6];
    float* out = (float*)d_out;
    float* ws  = (float*)d_ws;

    float* counts = ws;                   // 1024
    float* dw     = ws + 1024;            // 262144
    float* csf    = ws + 263168;          // 1024
    float* se2    = ws + 264192;          // 1024
    float* nemb   = ws + 265216;          // 262144
    int*   idx    = (int*)(ws + 527360);  // 131072 ints
    uint4* embst  = (uint4*)(ws + 658432);// 65536 uint4 = 1 MB (16B-aligned offset)

    hipMemsetAsync(counts, 0, (1024 + 262144) * sizeof(float), stream);
    hipMemsetAsync(out + 33554432, 0, 2 * sizeof(float), stream);

    vq_sume2  <<<4,    256, 0, stream>>>(emb1, emb2, se2);
    vq_embcvt <<<256,  256, 0, stream>>>(emb1, emb2, embst);
    vq_argmin3<<<2048, 512, 0, stream>>>(x, embst, se2, counts, idx);
    vq_dw     <<<128,  256, 0, stream>>>(x, idx, dw);
    vq_stats  <<<1,    512, 0, stream>>>(counts, cs1, cs2, csf, out);
    vq_newemb <<<256,  256, 0, stream>>>(dw, w1, w2, csf, nemb);
    vq_out    <<<1024, 256, 0, stream>>>(x, nemb, idx, out);
}

// Round 4
// 409.530 us; speedup vs baseline: 5.3938x; 1.9528x over previous
//
#include <hip/hip_runtime.h>

typedef short short8 __attribute__((ext_vector_type(8)));
typedef float f32x4 __attribute__((ext_vector_type(4)));

#define NK 512
#define SUBD 256
#define TT 2048
#define BD 512
#define NROWS 65536
#define DECAYF 0.99f
#define OMDF 0.01f
#define EPSF 1e-5f
#define FLT_BIG 3.402823466e+38f

static __device__ __forceinline__ ushort f2bf(float f) {
    uint u = __float_as_uint(f);
    u += 0x7FFFu + ((u >> 16) & 1u);
    return (ushort)(u >> 16);
}
static __device__ __forceinline__ float bf2f(ushort h) {
    return __uint_as_float(((uint)h) << 16);
}
static __device__ __forceinline__ float unpack2(uint u) {
    // u = (hi<<16)|lo ; value = hi + lo
    return __uint_as_float(u & 0xffff0000u) + __uint_as_float(u << 16);
}
union UCast { uint4 u; short8 s; };
static __device__ __forceinline__ short8 as_s8(uint4 v) { UCast c; c.u = v; return c.s; }

// ---------------- P0: sume2[h][k] = sum_c emb[k][c]^2 (exact fp32) ----------------
__global__ __launch_bounds__(256) void vq_sume2(const float* __restrict__ emb1,
                                                const float* __restrict__ emb2,
                                                float* __restrict__ sume2) {
    int r = blockIdx.x * 256 + threadIdx.x;
    const float* e = (r >> 9) ? emb2 : emb1;
    const float* row = e + (size_t)(r & 511) * SUBD;
    float s = 0.f;
#pragma unroll 8
    for (int i = 0; i < 64; ++i) {
        float4 v = *reinterpret_cast<const float4*>(row + i * 4);
        s += v.x * v.x + v.y * v.y + v.z * v.z + v.w * v.w;
    }
    sume2[r] = s;
}

// ---------------- P1: pre-convert emb to split-bf16, pre-swizzled staged layout ----
__global__ __launch_bounds__(256) void vq_embcvt(const float* __restrict__ emb1,
                                                 const float* __restrict__ emb2,
                                                 uint4* __restrict__ embst) {
    int id = blockIdx.x * 256 + threadIdx.x;      // 0..65535
    int h   = id >> 15;
    int s   = (id >> 11) & 15;
    int spl = (id >> 10) & 1;
    int k   = (id >> 2) & 255;
    int gp  = id & 3;
    int kh = s >> 3, cs = s & 7;
    int gl = gp ^ (k & 3);                        // un-swizzle to logical c-group
    const float* e = h ? emb2 : emb1;
    const float* src = e + (size_t)(kh * 256 + k) * SUBD + cs * 32 + gl * 8;
    float4 v0 = *reinterpret_cast<const float4*>(src);
    float4 v1 = *reinterpret_cast<const float4*>(src + 4);
    float f[8] = {v0.x, v0.y, v0.z, v0.w, v1.x, v1.y, v1.z, v1.w};
    ushort o[8];
#pragma unroll
    for (int i = 0; i < 8; ++i) {
        ushort hh = f2bf(f[i]);
        o[i] = spl ? f2bf(f[i] - bf2f(hh)) : hh;
    }
    uint4 d;
    d.x = o[0] | ((uint)o[1] << 16);
    d.y = o[2] | ((uint)o[3] << 16);
    d.z = o[4] | ((uint)o[5] << 16);
    d.w = o[6] | ((uint)o[7] << 16);
    embst[id] = d;
}

// ---------------- A: argmin via split-bf16 MFMA (+ optional xT dump) ----------------
__global__ __launch_bounds__(512) void vq_argmin3(const float* __restrict__ x,
                                                  const uint4* __restrict__ embst,
                                                  const float* __restrict__ sume2,
                                                  float* __restrict__ counts,
                                                  int* __restrict__ idx_out,
                                                  uint* __restrict__ xt) {
    __shared__ uint4 Ah[64 * 32];     // 32 KB  x_hi, XOR-swizzled 16B groups
    __shared__ uint4 Al[64 * 32];     // 32 KB  x_lo
    __shared__ uint4 Bb[2][2048];     // 64 KB  emb tile dbuf
    __shared__ float f2s[64];
    __shared__ float se_l[512];
    __shared__ float wbd[4][64];
    __shared__ int   wbk[4][64];

    const int tid = threadIdx.x;
    const int bid = blockIdx.x;
    const int h  = bid & 1;
    const int rb = bid >> 1;
    const int b  = rb >> 5;
    const int t0 = (rb & 31) << 6;

    if (tid < 64) f2s[tid] = 0.f;
    se_l[tid & 511] = sume2[h * NK + (tid & 511)];
    __syncthreads();

    // ---- stage A: transpose x -> LDS as bf16 hi/lo, swizzled ----
    {
        const int r  = tid & 63;
        const int cq = tid >> 6;
        const float* xb = x + ((size_t)b * BD + h * 256) * TT + t0 + r;
        float f2p = 0.f;
#pragma unroll
        for (int it = 0; it < 4; ++it) {
            const int c0 = cq * 32 + it * 8;
            float v[8];
#pragma unroll
            for (int j = 0; j < 8; ++j) v[j] = xb[(size_t)(c0 + j) * TT];
            ushort hi[8], lo[8];
#pragma unroll
            for (int j = 0; j < 8; ++j) {
                hi[j] = f2bf(v[j]);
                lo[j] = f2bf(v[j] - bf2f(hi[j]));
                f2p += v[j] * v[j];
            }
            uint4 uh, ul;
            uh.x = hi[0] | ((uint)hi[1] << 16); uh.y = hi[2] | ((uint)hi[3] << 16);
            uh.z = hi[4] | ((uint)hi[5] << 16); uh.w = hi[6] | ((uint)hi[7] << 16);
            ul.x = lo[0] | ((uint)lo[1] << 16); ul.y = lo[2] | ((uint)lo[3] << 16);
            ul.z = lo[4] | ((uint)lo[5] << 16); ul.w = lo[6] | ((uint)lo[7] << 16);
            const int phys = (c0 >> 3) ^ (r & 7);
            Ah[r * 32 + phys] = uh;
            Al[r * 32 + phys] = ul;
        }
        atomicAdd(&f2s[r], f2p);
    }
    {
        const uint4* src = embst + (size_t)h * 32768;
#pragma unroll
        for (int i = 0; i < 4; ++i) Bb[0][tid + i * 512] = src[tid + i * 512];
    }
    __syncthreads();

    const int l   = tid & 63;
    const int w   = tid >> 6;
    const int wr  = w >> 2, wk = w & 3;
    const int l15 = l & 15, l4 = l >> 4;
    const int bBase = l15 * 4 + (l4 ^ (l & 3));

    float bd8[8]; int bk8[8];
#pragma unroll
    for (int i = 0; i < 8; ++i) { bd8[i] = FLT_BIG; bk8[i] = 0; }

    int buf = 0;
    for (int kh = 0; kh < 2; ++kh) {
        f32x4 acc[2][4];
#pragma unroll
        for (int rg = 0; rg < 2; ++rg)
#pragma unroll
            for (int kg = 0; kg < 4; ++kg) acc[rg][kg] = (f32x4)0.f;

        for (int cs = 0; cs < 8; ++cs) {
            const int s = kh * 8 + cs;
            uint4 st[4];
            const bool pf = (s < 15);
            if (pf) {
                const uint4* src = embst + (size_t)h * 32768 + (size_t)(s + 1) * 2048;
#pragma unroll
                for (int i = 0; i < 4; ++i) st[i] = src[tid + i * 512];
            }
            short8 ah[2], al[2];
#pragma unroll
            for (int rg = 0; rg < 2; ++rg) {
                const int row = wr * 32 + rg * 16 + l15;
                const int ia = row * 32 + ((cs * 4 + l4) ^ (row & 7));
                ah[rg] = as_s8(Ah[ia]);
                al[rg] = as_s8(Al[ia]);
            }
            short8 bh[4], bl[4];
#pragma unroll
            for (int kg = 0; kg < 4; ++kg) {
                const int ib = wk * 256 + kg * 64 + bBase;
                bh[kg] = as_s8(Bb[buf][ib]);
                bl[kg] = as_s8(Bb[buf][1024 + ib]);
            }
#pragma unroll
            for (int rg = 0; rg < 2; ++rg)
#pragma unroll
                for (int kg = 0; kg < 4; ++kg) {
                    acc[rg][kg] = __builtin_amdgcn_mfma_f32_16x16x32_bf16(ah[rg], bh[kg], acc[rg][kg], 0, 0, 0);
                    acc[rg][kg] = __builtin_amdgcn_mfma_f32_16x16x32_bf16(ah[rg], bl[kg], acc[rg][kg], 0, 0, 0);
                    acc[rg][kg] = __builtin_amdgcn_mfma_f32_16x16x32_bf16(al[rg], bh[kg], acc[rg][kg], 0, 0, 0);
                }
            if (pf) {
#pragma unroll
                for (int i = 0; i < 4; ++i) Bb[buf ^ 1][tid + i * 512] = st[i];
            }
            __syncthreads();
            buf ^= 1;
        }
#pragma unroll
        for (int rg = 0; rg < 2; ++rg)
#pragma unroll
            for (int kg = 0; kg < 4; ++kg) {
                const int k = kh * 256 + wk * 64 + kg * 16 + l15;
                const float se = se_l[k];
#pragma unroll
                for (int reg = 0; reg < 4; ++reg) {
                    const int row = wr * 32 + rg * 16 + l4 * 4 + reg;
                    const float d = (f2s[row] + se) - 2.0f * acc[rg][kg][reg];
                    const int i8 = rg * 4 + reg;
                    if (d < bd8[i8]) { bd8[i8] = d; bk8[i8] = k; }
                }
            }
    }

#pragma unroll
    for (int m = 1; m < 16; m <<= 1) {
#pragma unroll
        for (int i = 0; i < 8; ++i) {
            const float od = __shfl_xor(bd8[i], m);
            const int   ok = __shfl_xor(bk8[i], m);
            if (od < bd8[i] || (od == bd8[i] && ok < bk8[i])) { bd8[i] = od; bk8[i] = ok; }
        }
    }
    if (l15 == 0) {
#pragma unroll
        for (int i = 0; i < 8; ++i) {
            const int rg = i >> 2, reg = i & 3;
            const int rr = wr * 32 + rg * 16 + l4 * 4 + reg;
            wbd[wk][rr] = bd8[i]; wbk[wk][rr] = bk8[i];
        }
    }
    __syncthreads();
    if (tid < 64) {
        float bd = wbd[0][tid]; int bk = wbk[0][tid];
#pragma unroll
        for (int q = 1; q < 4; ++q) {
            const float od = wbd[q][tid]; const int ok = wbk[q][tid];
            if (od < bd || (od == bd && ok < bk)) { bd = od; bk = ok; }
        }
        const int rglob = b * TT + t0 + tid;
        idx_out[h * NROWS + rglob] = bk;
        atomicAdd(&counts[(h << 9) + bk], 1.0f);
    }

    // ---- dump transposed split-bf16 x to global (packed hi<<16|lo) ----
    if (xt) {
        uint* dst = xt + ((size_t)h * NROWS + (size_t)b * TT + t0) * 256;
#pragma unroll
        for (int it = 0; it < 4; ++it) {
            const int j = tid + it * 512;       // 0..2047
            const int row = j >> 5, phys = j & 31;
            const int gl = phys ^ (row & 7);
            uint4 h4 = Ah[j];
            uint4 l4v = Al[j];
            uint4 o0, o1;
            o0.x = ((h4.x & 0xffffu) << 16) | (l4v.x & 0xffffu);
            o0.y = (h4.x & 0xffff0000u) | (l4v.x >> 16);
            o0.z = ((h4.y & 0xffffu) << 16) | (l4v.y & 0xffffu);
            o0.w = (h4.y & 0xffff0000u) | (l4v.y >> 16);
            o1.x = ((h4.z & 0xffffu) << 16) | (l4v.z & 0xffffu);
            o1.y = (h4.z & 0xffff0000u) | (l4v.z >> 16);
            o1.z = ((h4.w & 0xffffu) << 16) | (l4v.w & 0xffffu);
            o1.w = (h4.w & 0xffff0000u) | (l4v.w >> 16);
            uint* dp = dst + (size_t)row * 256 + gl * 8;
            *reinterpret_cast<uint4*>(dp)     = o0;
            *reinterpret_cast<uint4*>(dp + 4) = o1;
        }
    }
}

// ---------------- B-fast: cluster-major segmented sum -> new_emb directly ----------
// grid 1024 = (h,k); block 256 = 4 waves. Phase 1: ballot-compaction scan of idx
// (deterministic). Phase 2: thread owns c, sums cluster rows from xT.
__global__ __launch_bounds__(256) void vq_dwseg(const uint* __restrict__ xt,
                                                const int* __restrict__ idx,
                                                const float* __restrict__ w1,
                                                const float* __restrict__ w2,
                                                const float* __restrict__ cs_final,
                                                float* __restrict__ new_emb) {
    __shared__ ushort rows_l[4 * 512];
    __shared__ int cnt_w[4];
    const int tid = threadIdx.x;
    const int h = blockIdx.x >> 9;
    const int k = blockIdx.x & 511;
    const int w = tid >> 6;
    const int lane = tid & 63;

    // ---- phase 1: wave w scans rows [w*16384, (w+1)*16384) ----
    {
        const int* ip = idx + h * NROWS + w * 16384;
        int cnt = 0;
        for (int step = 0; step < 256; ++step) {
            const int rl = step * 64 + lane;
            const bool match = (ip[rl] == k);
            const unsigned long long m = __ballot(match);
            if (match) {
                const int pos = cnt + __popcll(m & ((1ull << lane) - 1ull));
                if (pos < 512) rows_l[w * 512 + pos] = (ushort)(w * 16384 + rl);
            }
            cnt += __popcll(m);
        }
        if (lane == 0) cnt_w[w] = (cnt < 512) ? cnt : 512;
    }
    __syncthreads();

    // ---- phase 2: thread owns channel c = tid ----
    const uint* xrow = xt + (size_t)h * NROWS * 256 + tid;
    float acc = 0.f;
    for (int s = 0; s < 4; ++s) {
        const int n = cnt_w[s];
        const ushort* rl = &rows_l[s * 512];
        int i = 0;
        for (; i + 4 <= n; i += 4) {
            const uint u0 = xrow[(size_t)rl[i + 0] << 8];
            const uint u1 = xrow[(size_t)rl[i + 1] << 8];
            const uint u2 = xrow[(size_t)rl[i + 2] << 8];
            const uint u3 = xrow[(size_t)rl[i + 3] << 8];
            acc += unpack2(u0) + unpack2(u1) + unpack2(u2) + unpack2(u3);
        }
        for (; i < n; ++i) acc += unpack2(xrow[(size_t)rl[i] << 8]);
    }
    const float* wsrc = h ? w2 : w1;
    const float nv = (DECAYF * wsrc[(size_t)k * SUBD + tid] + OMDF * acc)
                     / cs_final[(h << 9) + k];
    new_emb[((size_t)(h << 9) + k) * SUBD + tid] = nv;
}

// ---------------- B-fallback: dw via LDS-privatized histogram ----------------
__global__ __launch_bounds__(256) void vq_dw(const float* __restrict__ x,
                                             const int* __restrict__ idx,
                                             float* __restrict__ dw) {
    __shared__ float dwp[64 * 512];
    const int tid = threadIdx.x;
    const int h = blockIdx.x & 1;
    const int cr = (blockIdx.x >> 1) & 3;
    const int slab = blockIdx.x >> 3;
#pragma unroll 8
    for (int i = 0; i < 128; ++i) dwp[tid + i * 256] = 0.f;
    __syncthreads();
    for (int it = 0; it < 16; ++it) {
        const int r = (slab << 12) + (it << 8) + tid;
        const int k = idx[(h << 16) + r];
        const float* xb = x + ((size_t)(r >> 11) * BD + (h << 8) + (cr << 6)) * TT + (r & 2047);
#pragma unroll
        for (int c = 0; c < 64; ++c)
            atomicAdd(&dwp[(c << 9) + k], xb[(size_t)c * TT]);
    }
    __syncthreads();
#pragma unroll 8
    for (int i = 0; i < 128; ++i) {
        const int j = tid + i * 256;
        const int k = j & 511;
        const int c = j >> 9;
        atomicAdd(&dw[(size_t)((h << 9) + k) * SUBD + (cr << 6) + c], dwp[j]);
    }
}

// ---------------- D1: EMA cluster-size smoothing + perplexity ----------------
__global__ void vq_stats(const float* __restrict__ counts,
                         const float* __restrict__ cs_in1,
                         const float* __restrict__ cs_in2,
                         float* __restrict__ cs_final,
                         float* __restrict__ out) {
    __shared__ float red[512];
    const int k = threadIdx.x;
    float perp_tot = 0.f;
    for (int h = 0; h < 2; ++h) {
        const float* csin = h ? cs_in2 : cs_in1;
        float cnt = counts[(h << 9) + k];
        float csn = DECAYF * csin[k] + OMDF * cnt;
        red[k] = csn;
        __syncthreads();
        for (int s = 256; s > 0; s >>= 1) {
            if (k < s) red[k] += red[k + s];
            __syncthreads();
        }
        float n = red[0];
        __syncthreads();
        cs_final[(h << 9) + k] = (csn + EPSF) / (n + 512.0f * EPSF) * n;
        float p = cnt * (1.0f / 65536.0f);
        float e = p * logf(p + 1e-10f);
        red[k] = e;
        __syncthreads();
        for (int s = 256; s > 0; s >>= 1) {
            if (k < s) red[k] += red[k + s];
            __syncthreads();
        }
        if (k == 0) perp_tot += expf(-red[0]);
        __syncthreads();
    }
    if (k == 0) out[33554433] = perp_tot;
}

// ---------------- D2 (fallback): new_emb = (decay*ema_w + 0.01*dw) / cs -----------
__global__ __launch_bounds__(256) void vq_newemb(const float* __restrict__ dw,
                                                 const float* __restrict__ w1,
                                                 const float* __restrict__ w2,
                                                 const float* __restrict__ cs_final,
                                                 float* __restrict__ new_emb) {
    int g = blockIdx.x * 256 + threadIdx.x;
    int h = g >> 15;
    int k = (g >> 6) & 511;
    const float* wi = h ? w2 : w1;
    float4 d4 = *reinterpret_cast<const float4*>(dw + (size_t)g * 4);
    float4 w4 = *reinterpret_cast<const float4*>(wi + (size_t)(g & 32767) * 4);
    float cs = cs_final[(h << 9) + k];
    float4 o;
    o.x = (DECAYF * w4.x + OMDF * d4.x) / cs;
    o.y = (DECAYF * w4.y + OMDF * d4.y) / cs;
    o.z = (DECAYF * w4.z + OMDF * d4.z) / cs;
    o.w = (DECAYF * w4.w + OMDF * d4.w) / cs;
    *reinterpret_cast<float4*>(new_emb + (size_t)g * 4) = o;
}

// ---------------- E: gather + output + vq_loss ----------------
__global__ __launch_bounds__(256) void vq_out(const float* __restrict__ x,
                                              const float* __restrict__ nemb,
                                              const int* __restrict__ idx,
                                              float* __restrict__ out) {
    __shared__ int idx_l[2][64];
    __shared__ float wsum[4];
    const int tid = threadIdx.x;
    const int b = blockIdx.x >> 5;
    const int t0 = (blockIdx.x & 31) << 6;
    if (tid < 128) {
        int hh = tid >> 6, t = tid & 63;
        idx_l[hh][t] = idx[hh * NROWS + b * TT + t0 + t];
    }
    __syncthreads();
    const int tq = tid & 15;
    const int cw = tid >> 4;
    const int k0 = idx_l[0][tq * 4 + 0], k1 = idx_l[0][tq * 4 + 1];
    const int k2 = idx_l[0][tq * 4 + 2], k3 = idx_l[0][tq * 4 + 3];
    const int m0 = idx_l[1][tq * 4 + 0], m1 = idx_l[1][tq * 4 + 1];
    const int m2 = idx_l[1][tq * 4 + 2], m3 = idx_l[1][tq * 4 + 3];
    float lsum = 0.f;
    for (int i = 0; i < 32; ++i) {
        const int c = cw + i * 16;
        const int hh = c >> 8, cp = c & 255;
        const size_t base = ((size_t)b * BD + c) * TT + t0 + tq * 4;
        float4 xv = *reinterpret_cast<const float4*>(x + base);
        const size_t eb = (size_t)(hh << 9) * SUBD + cp;
        float q0 = nemb[eb + (size_t)(hh ? m0 : k0) * SUBD];
        float q1 = nemb[eb + (size_t)(hh ? m1 : k1) * SUBD];
        float q2 = nemb[eb + (size_t)(hh ? m2 : k2) * SUBD];
        float q3 = nemb[eb + (size_t)(hh ? m3 : k3) * SUBD];
        float4 o; float t1;
        t1 = q0 - xv.x; o.x = xv.x + t1; lsum += t1 * t1;
        t1 = q1 - xv.y; o.y = xv.y + t1; lsum += t1 * t1;
        t1 = q2 - xv.z; o.z = xv.z + t1; lsum += t1 * t1;
        t1 = q3 - xv.w; o.w = xv.w + t1; lsum += t1 * t1;
        *reinterpret_cast<float4*>(out + base) = o;
    }
#pragma unroll
    for (int m = 1; m < 64; m <<= 1) lsum += __shfl_xor(lsum, m);
    if ((tid & 63) == 0) wsum[tid >> 6] = lsum;
    __syncthreads();
    if (tid == 0) {
        float s = wsum[0] + wsum[1] + wsum[2] + wsum[3];
        atomicAdd(out + 33554432, s * (0.25f / 33554432.0f));
    }
}

extern "C" void kernel_launch(void* const* d_in, const int* in_sizes, int n_in,
                              void* d_out, int out_size, void* d_ws, size_t ws_size,
                              hipStream_t stream) {
    const float* x    = (const float*)d_in[0];
    const float* emb1 = (const float*)d_in[1];
    const float* emb2 = (const float*)d_in[2];
    const float* cs1  = (const float*)d_in[3];
    const float* w1   = (const float*)d_in[4];
    const float* cs2  = (const float*)d_in[5];
    const float* w2   = (const float*)d_in[6];
    float* out = (float*)d_out;
    float* ws  = (float*)d_ws;

    float* counts = ws;                    // 1024
    float* csf    = ws + 1024;             // 1024
    float* se2    = ws + 2048;             // 1024
    float* nemb   = ws + 3072;             // 262144
    int*   idx    = (int*)(ws + 265216);   // 131072 ints
    uint4* embst  = (uint4*)(ws + 396288); // 65536 uint4 (1 MB)
    float* dw     = ws + 658432;           // 262144 (fallback only)
    uint*  xT     = (uint*)(ws + 920576);  // 33554432 uints (134 MB, fast path)

    const size_t NEED = (size_t)(920576 + 33554432) * 4;
    const bool fast = (ws_size >= NEED);

    hipMemsetAsync(counts, 0, 1024 * sizeof(float), stream);
    hipMemsetAsync(out + 33554432, 0, 2 * sizeof(float), stream);

    vq_sume2  <<<4,   256, 0, stream>>>(emb1, emb2, se2);
    vq_embcvt <<<256, 256, 0, stream>>>(emb1, emb2, embst);

    if (fast) {
        vq_argmin3<<<2048, 512, 0, stream>>>(x, embst, se2, counts, idx, xT);
        vq_stats  <<<1,    512, 0, stream>>>(counts, cs1, cs2, csf, out);
        vq_dwseg  <<<1024, 256, 0, stream>>>(xT, idx, w1, w2, csf, nemb);
    } else {
        hipMemsetAsync(dw, 0, 262144 * sizeof(float), stream);
        vq_argmin3<<<2048, 512, 0, stream>>>(x, embst, se2, counts, idx, nullptr);
        vq_dw     <<<128,  256, 0, stream>>>(x, idx, dw);
        vq_stats  <<<1,    512, 0, stream>>>(counts, cs1, cs2, csf, out);
        vq_newemb <<<256,  256, 0, stream>>>(dw, w1, w2, csf, nemb);
    }
    vq_out<<<1024, 256, 0, stream>>>(x, nemb, idx, out);
}

// Round 5
// 399.246 us; speedup vs baseline: 5.5327x; 1.0258x over previous
//
#include <hip/hip_runtime.h>

typedef short short8 __attribute__((ext_vector_type(8)));
typedef float f32x4 __attribute__((ext_vector_type(4)));

#define NK 512
#define SUBD 256
#define TT 2048
#define BD 512
#define NROWS 65536
#define DECAYF 0.99f
#define OMDF 0.01f
#define EPSF 1e-5f
#define FLT_BIG 3.402823466e+38f

static __device__ __forceinline__ ushort f2bf(float f) {
    uint u = __float_as_uint(f);
    u += 0x7FFFu + ((u >> 16) & 1u);
    return (ushort)(u >> 16);
}
static __device__ __forceinline__ float bf2f(ushort h) {
    return __uint_as_float(((uint)h) << 16);
}
union UCast { uint4 u; short8 s; };
static __device__ __forceinline__ short8 as_s8(uint4 v) { UCast c; c.u = v; return c.s; }

// async global->LDS, 16B per lane; LDS dest must be wave-uniform base (+lane*16)
static __device__ __forceinline__ void gload_lds16(const uint4* g, uint4* l) {
    __builtin_amdgcn_global_load_lds(
        (const __attribute__((address_space(1))) void*)g,
        (__attribute__((address_space(3))) void*)l, 16, 0, 0);
}

// ---------------- P0: sume2[h][k] = sum_c emb[k][c]^2 (exact fp32) ----------------
__global__ __launch_bounds__(256) void vq_sume2(const float* __restrict__ emb1,
                                                const float* __restrict__ emb2,
                                                float* __restrict__ sume2) {
    int r = blockIdx.x * 256 + threadIdx.x;
    const float* e = (r >> 9) ? emb2 : emb1;
    const float* row = e + (size_t)(r & 511) * SUBD;
    float s = 0.f;
#pragma unroll 8
    for (int i = 0; i < 64; ++i) {
        float4 v = *reinterpret_cast<const float4*>(row + i * 4);
        s += v.x * v.x + v.y * v.y + v.z * v.z + v.w * v.w;
    }
    sume2[r] = s;
}

// ---------------- P1: emb -> split-bf16, pre-swizzled staged layout ----------------
// embst[h][s=kh*8+cs][spl][k 0..255][pg 0..3]; phys pg holds logical group pg^((k>>1)&3)
__global__ __launch_bounds__(256) void vq_embcvt(const float* __restrict__ emb1,
                                                 const float* __restrict__ emb2,
                                                 uint4* __restrict__ embst) {
    int id = blockIdx.x * 256 + threadIdx.x;      // 0..65535
    int h   = id >> 15;
    int s   = (id >> 11) & 15;
    int spl = (id >> 10) & 1;
    int k   = (id >> 2) & 255;
    int gp  = id & 3;
    int kh = s >> 3, cs = s & 7;
    int gl = gp ^ ((k >> 1) & 3);                 // un-swizzle to logical c-group
    const float* e = h ? emb2 : emb1;
    const float* src = e + (size_t)(kh * 256 + k) * SUBD + cs * 32 + gl * 8;
    float4 v0 = *reinterpret_cast<const float4*>(src);
    float4 v1 = *reinterpret_cast<const float4*>(src + 4);
    float f[8] = {v0.x, v0.y, v0.z, v0.w, v1.x, v1.y, v1.z, v1.w};
    ushort o[8];
#pragma unroll
    for (int i = 0; i < 8; ++i) {
        ushort hh = f2bf(f[i]);
        o[i] = spl ? f2bf(f[i] - bf2f(hh)) : hh;
    }
    uint4 d;
    d.x = o[0] | ((uint)o[1] << 16);
    d.y = o[2] | ((uint)o[3] << 16);
    d.z = o[4] | ((uint)o[5] << 16);
    d.w = o[6] | ((uint)o[7] << 16);
    embst[id] = d;
}

// ---------------- X1: x -> transposed split-bf16 planes (argmin LDS order) + f2 ----
// plane[h][rblk][row 64][physchunk 32] (uint4); phys = chunk ^ (row&7)
__global__ __launch_bounds__(512) void vq_x1(const float* __restrict__ x,
                                             uint4* __restrict__ planeH,
                                             uint4* __restrict__ planeL,
                                             float* __restrict__ f2g) {
    __shared__ uint4 AhL[2048];
    __shared__ uint4 AlL[2048];
    __shared__ float f2p[512];
    const int tid = threadIdx.x;
    const int h  = blockIdx.x & 1;
    const int rb = blockIdx.x >> 1;
    const int b  = rb >> 5;
    const int t0 = (rb & 31) << 6;
    const int r  = tid & 63;
    const int co = (tid >> 6) * 32;
    const float* xb = x + ((size_t)b * BD + h * 256 + co) * TT + t0 + r;
    float f2 = 0.f;
#pragma unroll
    for (int j4 = 0; j4 < 4; ++j4) {
        float v[8];
#pragma unroll
        for (int j = 0; j < 8; ++j) v[j] = xb[(size_t)(j4 * 8 + j) * TT];
        ushort hi[8], lo[8];
#pragma unroll
        for (int j = 0; j < 8; ++j) {
            hi[j] = f2bf(v[j]);
            lo[j] = f2bf(v[j] - bf2f(hi[j]));
            f2 += v[j] * v[j];
        }
        uint4 uh, ul;
        uh.x = hi[0] | ((uint)hi[1] << 16); uh.y = hi[2] | ((uint)hi[3] << 16);
        uh.z = hi[4] | ((uint)hi[5] << 16); uh.w = hi[6] | ((uint)hi[7] << 16);
        ul.x = lo[0] | ((uint)lo[1] << 16); ul.y = lo[2] | ((uint)lo[3] << 16);
        ul.z = lo[4] | ((uint)lo[5] << 16); ul.w = lo[6] | ((uint)lo[7] << 16);
        const int chunk = (co >> 3) + j4;
        const int phys = chunk ^ (r & 7);
        AhL[r * 32 + phys] = uh;
        AlL[r * 32 + phys] = ul;
    }
    f2p[tid] = f2;
    __syncthreads();
    const size_t pb = (size_t)(h * 1024 + rb) * 2048;
#pragma unroll
    for (int i = 0; i < 4; ++i) {
        planeH[pb + tid + i * 512] = AhL[tid + i * 512];
        planeL[pb + tid + i * 512] = AlL[tid + i * 512];
    }
    if (tid < 64) {
        float s = 0.f;
#pragma unroll
        for (int g = 0; g < 8; ++g) s += f2p[g * 64 + tid];   // ascending c order
        f2g[h * NROWS + rb * 64 + tid] = s;
    }
}

// ---------------- A: argmin, DMA-staged MFMA pipeline ----------------
// grid 2048 = (rblk,h); 512 thr = 8 waves (2 wr x 4 wk); wave tile 32r x 64k
__global__ __launch_bounds__(512) void vq_argmin4(const uint4* __restrict__ planeH,
                                                  const uint4* __restrict__ planeL,
                                                  const uint4* __restrict__ embst,
                                                  const float* __restrict__ f2g,
                                                  const float* __restrict__ sume2,
                                                  float* __restrict__ counts,
                                                  int* __restrict__ idx_out) {
    __shared__ uint4 Ah[2048];        // 32 KB
    __shared__ uint4 Al[2048];        // 32 KB
    __shared__ uint4 Bb[2][2048];     // 64 KB dbuf
    __shared__ float f2s[64];
    __shared__ float se_l[512];
    __shared__ float wbd[4][64];
    __shared__ int   wbk[4][64];

    const int tid = threadIdx.x;
    const int h  = blockIdx.x & 1;
    const int rb = blockIdx.x >> 1;
    const int wv = tid >> 6;
    const int lane = tid & 63;

    // ---- DMA prologue: A (hi+lo) + B stage 0 ----
    {
        const size_t pb = (size_t)(h * 1024 + rb) * 2048;
        const uint4* sH = planeH + pb;
        const uint4* sL = planeL + pb;
        const uint4* sB = embst + (size_t)h * 32768;
#pragma unroll
        for (int i = 0; i < 4; ++i) {
            const int o = wv * 256 + i * 64;
            gload_lds16(sH + o + lane, &Ah[o]);
            gload_lds16(sL + o + lane, &Al[o]);
            gload_lds16(sB + o + lane, &Bb[0][o]);
        }
    }
    se_l[tid] = sume2[h * NK + tid];
    if (tid < 64) f2s[tid] = f2g[h * NROWS + rb * 64 + tid];
    __syncthreads();      // drains vmcnt -> A + B0 resident

    const int l15 = lane & 15, l4 = lane >> 4;
    const int wr = wv >> 2, wk = wv & 3;
    const int bBase = l15 * 4 + (l4 ^ ((l15 >> 1) & 3));

    float bd8[8]; int bk8[8];
#pragma unroll
    for (int i = 0; i < 8; ++i) { bd8[i] = FLT_BIG; bk8[i] = 0; }

    int buf = 0;
    for (int kh = 0; kh < 2; ++kh) {
        f32x4 acc[2][4];
#pragma unroll
        for (int rg = 0; rg < 2; ++rg)
#pragma unroll
            for (int kg = 0; kg < 4; ++kg) acc[rg][kg] = (f32x4)0.f;

        for (int cs = 0; cs < 8; ++cs) {
            const int s = kh * 8 + cs;
            if (s < 15) {   // async prefetch stage s+1 (in flight across MFMAs)
                const uint4* sB = embst + (size_t)h * 32768 + (size_t)(s + 1) * 2048;
#pragma unroll
                for (int i = 0; i < 4; ++i) {
                    const int o = wv * 256 + i * 64;
                    gload_lds16(sB + o + lane, &Bb[buf ^ 1][o]);
                }
            }
            short8 ah[2], al[2];
#pragma unroll
            for (int rg = 0; rg < 2; ++rg) {
                const int row = wr * 32 + rg * 16 + l15;
                const int ia = row * 32 + ((cs * 4 + l4) ^ (row & 7));
                ah[rg] = as_s8(Ah[ia]);
                al[rg] = as_s8(Al[ia]);
            }
            short8 bh[4], bl[4];
#pragma unroll
            for (int kg = 0; kg < 4; ++kg) {
                const int ib = wk * 256 + kg * 64 + bBase;
                bh[kg] = as_s8(Bb[buf][ib]);
                bl[kg] = as_s8(Bb[buf][1024 + ib]);
            }
#pragma unroll
            for (int rg = 0; rg < 2; ++rg)
#pragma unroll
                for (int kg = 0; kg < 4; ++kg) {
                    acc[rg][kg] = __builtin_amdgcn_mfma_f32_16x16x32_bf16(ah[rg], bh[kg], acc[rg][kg], 0, 0, 0);
                    acc[rg][kg] = __builtin_amdgcn_mfma_f32_16x16x32_bf16(ah[rg], bl[kg], acc[rg][kg], 0, 0, 0);
                    acc[rg][kg] = __builtin_amdgcn_mfma_f32_16x16x32_bf16(al[rg], bh[kg], acc[rg][kg], 0, 0, 0);
                }
            __syncthreads();   // stage s+1 landed; buf reads done before overwrite
            buf ^= 1;
        }
#pragma unroll
        for (int rg = 0; rg < 2; ++rg)
#pragma unroll
            for (int kg = 0; kg < 4; ++kg) {
                const int k = kh * 256 + wk * 64 + kg * 16 + l15;
                const float se = se_l[k];
#pragma unroll
                for (int reg = 0; reg < 4; ++reg) {
                    const int row = wr * 32 + rg * 16 + l4 * 4 + reg;
                    const float d = (f2s[row] + se) - 2.0f * acc[rg][kg][reg];
                    const int i8 = rg * 4 + reg;
                    if (d < bd8[i8]) { bd8[i8] = d; bk8[i8] = k; }
                }
            }
    }

#pragma unroll
    for (int m = 1; m < 16; m <<= 1) {
#pragma unroll
        for (int i = 0; i < 8; ++i) {
            const float od = __shfl_xor(bd8[i], m);
            const int   ok = __shfl_xor(bk8[i], m);
            if (od < bd8[i] || (od == bd8[i] && ok < bk8[i])) { bd8[i] = od; bk8[i] = ok; }
        }
    }
    if (l15 == 0) {
#pragma unroll
        for (int i = 0; i < 8; ++i) {
            const int rg = i >> 2, reg = i & 3;
            const int rr = wr * 32 + rg * 16 + l4 * 4 + reg;
            wbd[wk][rr] = bd8[i]; wbk[wk][rr] = bk8[i];
        }
    }
    __syncthreads();
    if (tid < 64) {
        float bd = wbd[0][tid]; int bk = wbk[0][tid];
#pragma unroll
        for (int q = 1; q < 4; ++q) {
            const float od = wbd[q][tid]; const int ok = wbk[q][tid];
            if (od < bd || (od == bd && ok < bk)) { bd = od; bk = ok; }
        }
        idx_out[h * NROWS + rb * 64 + tid] = bk;
        atomicAdd(&counts[(h << 9) + bk], 1.0f);
    }
}

// ---------------- B: cluster-major segmented sum from planes -> new_emb ------------
// grid 1024 = (h,k); 256 thr (thread owns channel c). Windowed scan: cap-safe.
__global__ __launch_bounds__(256) void vq_dwseg2(const uint4* __restrict__ planeH,
                                                 const uint4* __restrict__ planeL,
                                                 const int* __restrict__ idx,
                                                 const float* __restrict__ w1,
                                                 const float* __restrict__ w2,
                                                 const float* __restrict__ csf,
                                                 float* __restrict__ nemb) {
    __shared__ ushort rows_l[4][1024];
    __shared__ int cnt_w[4];
    const int tid = threadIdx.x;
    const int h = blockIdx.x >> 9;
    const int k = blockIdx.x & 511;
    const int w = tid >> 6, lane = tid & 63;
    const ushort* pH = (const ushort*)planeH;
    const ushort* pL = (const ushort*)planeL;
    const int c = tid;
    const size_t hbase = (size_t)h * 1024 * 16384;    // ushorts per half
    float acc = 0.f;
    for (int win = 0; win < 4; ++win) {
        {
            const int base = win * 16384 + w * 4096;
            const int* ip = idx + h * NROWS + base;
            int cnt = 0;
            for (int stp = 0; stp < 64; ++stp) {
                const int rl = stp * 64 + lane;
                const bool mt = (ip[rl] == k);
                const unsigned long long m = __ballot(mt);
                if (mt) {
                    const int pos = cnt + __popcll(m & ((1ull << lane) - 1ull));
                    if (pos < 1024) rows_l[w][pos] = (ushort)rl;
                }
                cnt += __popcll(m);
            }
            if (lane == 0) cnt_w[w] = (cnt < 1024) ? cnt : 1024;
        }
        __syncthreads();
        for (int s = 0; s < 4; ++s) {
            const int n = cnt_w[s];
            const int rbase = win * 16384 + s * 4096;
            for (int i = 0; i < n; ++i) {
                const int r = rbase + rows_l[s][i];
                const size_t off = hbase + (size_t)(r >> 6) * 16384 + (r & 63) * 256
                                 + (((c >> 3) ^ (r & 7)) << 3) + (c & 7);
                acc += bf2f(pH[off]) + bf2f(pL[off]);
            }
        }
        __syncthreads();
    }
    const float* wsrc = h ? w2 : w1;
    nemb[((size_t)(h << 9) + k) * SUBD + c] =
        (DECAYF * wsrc[(size_t)k * SUBD + c] + OMDF * acc) / csf[(h << 9) + k];
}

// ---------------- D1: EMA cluster-size smoothing + perplexity ----------------
__global__ void vq_stats(const float* __restrict__ counts,
                         const float* __restrict__ cs_in1,
                         const float* __restrict__ cs_in2,
                         float* __restrict__ cs_final,
                         float* __restrict__ out) {
    __shared__ float red[512];
    const int k = threadIdx.x;
    float perp_tot = 0.f;
    for (int h = 0; h < 2; ++h) {
        const float* csin = h ? cs_in2 : cs_in1;
        float cnt = counts[(h << 9) + k];
        float csn = DECAYF * csin[k] + OMDF * cnt;
        red[k] = csn;
        __syncthreads();
        for (int s = 256; s > 0; s >>= 1) {
            if (k < s) red[k] += red[k + s];
            __syncthreads();
        }
        float n = red[0];
        __syncthreads();
        cs_final[(h << 9) + k] = (csn + EPSF) / (n + 512.0f * EPSF) * n;
        float p = cnt * (1.0f / 65536.0f);
        float e = p * logf(p + 1e-10f);
        red[k] = e;
        __syncthreads();
        for (int s = 256; s > 0; s >>= 1) {
            if (k < s) red[k] += red[k + s];
            __syncthreads();
        }
        if (k == 0) perp_tot += expf(-red[0]);
        __syncthreads();
    }
    if (k == 0) out[33554433] = perp_tot;
}

// ---------------- fallback chain (ws too small for planes) ----------------
__global__ __launch_bounds__(512) void vq_argmin3(const float* __restrict__ x,
                                                  const uint4* __restrict__ embst,
                                                  const float* __restrict__ sume2,
                                                  float* __restrict__ counts,
                                                  int* __restrict__ idx_out) {
    __shared__ uint4 Ah[2048];
    __shared__ uint4 Al[2048];
    __shared__ uint4 Bb[2][2048];
    __shared__ float f2s[64];
    __shared__ float se_l[512];
    __shared__ float wbd[4][64];
    __shared__ int   wbk[4][64];
    const int tid = threadIdx.x;
    const int h  = blockIdx.x & 1;
    const int rb = blockIdx.x >> 1;
    const int b  = rb >> 5;
    const int t0 = (rb & 31) << 6;
    if (tid < 64) f2s[tid] = 0.f;
    se_l[tid] = sume2[h * NK + tid];
    __syncthreads();
    {
        const int r  = tid & 63;
        const int cq = tid >> 6;
        const float* xb = x + ((size_t)b * BD + h * 256) * TT + t0 + r;
        float f2p = 0.f;
#pragma unroll
        for (int it = 0; it < 4; ++it) {
            const int c0 = cq * 32 + it * 8;
            float v[8];
#pragma unroll
            for (int j = 0; j < 8; ++j) v[j] = xb[(size_t)(c0 + j) * TT];
            ushort hi[8], lo[8];
#pragma unroll
            for (int j = 0; j < 8; ++j) {
                hi[j] = f2bf(v[j]);
                lo[j] = f2bf(v[j] - bf2f(hi[j]));
                f2p += v[j] * v[j];
            }
            uint4 uh, ul;
            uh.x = hi[0] | ((uint)hi[1] << 16); uh.y = hi[2] | ((uint)hi[3] << 16);
            uh.z = hi[4] | ((uint)hi[5] << 16); uh.w = hi[6] | ((uint)hi[7] << 16);
            ul.x = lo[0] | ((uint)lo[1] << 16); ul.y = lo[2] | ((uint)lo[3] << 16);
            ul.z = lo[4] | ((uint)lo[5] << 16); ul.w = lo[6] | ((uint)lo[7] << 16);
            const int phys = (c0 >> 3) ^ (r & 7);
            Ah[r * 32 + phys] = uh;
            Al[r * 32 + phys] = ul;
        }
        atomicAdd(&f2s[r], f2p);
    }
    {
        const uint4* src = embst + (size_t)h * 32768;
#pragma unroll
        for (int i = 0; i < 4; ++i) Bb[0][tid + i * 512] = src[tid + i * 512];
    }
    __syncthreads();
    const int l = tid & 63;
    const int wv = tid >> 6;
    const int wr = wv >> 2, wk = wv & 3;
    const int l15 = l & 15, l4 = l >> 4;
    const int bBase = l15 * 4 + (l4 ^ ((l15 >> 1) & 3));
    float bd8[8]; int bk8[8];
#pragma unroll
    for (int i = 0; i < 8; ++i) { bd8[i] = FLT_BIG; bk8[i] = 0; }
    int buf = 0;
    for (int kh = 0; kh < 2; ++kh) {
        f32x4 acc[2][4];
#pragma unroll
        for (int rg = 0; rg < 2; ++rg)
#pragma unroll
            for (int kg = 0; kg < 4; ++kg) acc[rg][kg] = (f32x4)0.f;
        for (int cs = 0; cs < 8; ++cs) {
            const int s = kh * 8 + cs;
            uint4 st[4];
            const bool pf = (s < 15);
            if (pf) {
                const uint4* src = embst + (size_t)h * 32768 + (size_t)(s + 1) * 2048;
#pragma unroll
                for (int i = 0; i < 4; ++i) st[i] = src[tid + i * 512];
            }
            short8 ah[2], al[2];
#pragma unroll
            for (int rg = 0; rg < 2; ++rg) {
                const int row = wr * 32 + rg * 16 + l15;
                const int ia = row * 32 + ((cs * 4 + l4) ^ (row & 7));
                ah[rg] = as_s8(Ah[ia]);
                al[rg] = as_s8(Al[ia]);
            }
            short8 bh[4], bl[4];
#pragma unroll
            for (int kg = 0; kg < 4; ++kg) {
                const int ib = wk * 256 + kg * 64 + bBase;
                bh[kg] = as_s8(Bb[buf][ib]);
                bl[kg] = as_s8(Bb[buf][1024 + ib]);
            }
#pragma unroll
            for (int rg = 0; rg < 2; ++rg)
#pragma unroll
                for (int kg = 0; kg < 4; ++kg) {
                    acc[rg][kg] = __builtin_amdgcn_mfma_f32_16x16x32_bf16(ah[rg], bh[kg], acc[rg][kg], 0, 0, 0);
                    acc[rg][kg] = __builtin_amdgcn_mfma_f32_16x16x32_bf16(ah[rg], bl[kg], acc[rg][kg], 0, 0, 0);
                    acc[rg][kg] = __builtin_amdgcn_mfma_f32_16x16x32_bf16(al[rg], bh[kg], acc[rg][kg], 0, 0, 0);
                }
            if (pf) {
#pragma unroll
                for (int i = 0; i < 4; ++i) Bb[buf ^ 1][tid + i * 512] = st[i];
            }
            __syncthreads();
            buf ^= 1;
        }
#pragma unroll
        for (int rg = 0; rg < 2; ++rg)
#pragma unroll
            for (int kg = 0; kg < 4; ++kg) {
                const int k = kh * 256 + wk * 64 + kg * 16 + l15;
                const float se = se_l[k];
#pragma unroll
                for (int reg = 0; reg < 4; ++reg) {
                    const int row = wr * 32 + rg * 16 + l4 * 4 + reg;
                    const float d = (f2s[row] + se) - 2.0f * acc[rg][kg][reg];
                    const int i8 = rg * 4 + reg;
                    if (d < bd8[i8]) { bd8[i8] = d; bk8[i8] = k; }
                }
            }
    }
#pragma unroll
    for (int m = 1; m < 16; m <<= 1) {
#pragma unroll
        for (int i = 0; i < 8; ++i) {
            const float od = __shfl_xor(bd8[i], m);
            const int   ok = __shfl_xor(bk8[i], m);
            if (od < bd8[i] || (od == bd8[i] && ok < bk8[i])) { bd8[i] = od; bk8[i] = ok; }
        }
    }
    if (l15 == 0) {
#pragma unroll
        for (int i = 0; i < 8; ++i) {
            const int rg = i >> 2, reg = i & 3;
            const int rr = wr * 32 + rg * 16 + l4 * 4 + reg;
            wbd[wk][rr] = bd8[i]; wbk[wk][rr] = bk8[i];
        }
    }
    __syncthreads();
    if (tid < 64) {
        float bd = wbd[0][tid]; int bk = wbk[0][tid];
#pragma unroll
        for (int q = 1; q < 4; ++q) {
            const float od = wbd[q][tid]; const int ok = wbk[q][tid];
            if (od < bd || (od == bd && ok < bk)) { bd = od; bk = ok; }
        }
        idx_out[h * NROWS + b * TT + t0 + tid] = bk;
        atomicAdd(&counts[(h << 9) + bk], 1.0f);
    }
}

__global__ __launch_bounds__(256) void vq_dw(const float* __restrict__ x,
                                             const int* __restrict__ idx,
                                             float* __restrict__ dw) {
    __shared__ float dwp[64 * 512];
    const int tid = threadIdx.x;
    const int h = blockIdx.x & 1;
    const int cr = (blockIdx.x >> 1) & 3;
    const int slab = blockIdx.x >> 3;
#pragma unroll 8
    for (int i = 0; i < 128; ++i) dwp[tid + i * 256] = 0.f;
    __syncthreads();
    for (int it = 0; it < 16; ++it) {
        const int r = (slab << 12) + (it << 8) + tid;
        const int k = idx[(h << 16) + r];
        const float* xb = x + ((size_t)(r >> 11) * BD + (h << 8) + (cr << 6)) * TT + (r & 2047);
#pragma unroll
        for (int c = 0; c < 64; ++c)
            atomicAdd(&dwp[(c << 9) + k], xb[(size_t)c * TT]);
    }
    __syncthreads();
#pragma unroll 8
    for (int i = 0; i < 128; ++i) {
        const int j = tid + i * 256;
        atomicAdd(&dw[(size_t)((h << 9) + (j & 511)) * SUBD + (cr << 6) + (j >> 9)], dwp[j]);
    }
}

__global__ __launch_bounds__(256) void vq_newemb(const float* __restrict__ dw,
                                                 const float* __restrict__ w1,
                                                 const float* __restrict__ w2,
                                                 const float* __restrict__ cs_final,
                                                 float* __restrict__ new_emb) {
    int g = blockIdx.x * 256 + threadIdx.x;
    int h = g >> 15;
    int k = (g >> 6) & 511;
    const float* wi = h ? w2 : w1;
    float4 d4 = *reinterpret_cast<const float4*>(dw + (size_t)g * 4);
    float4 w4 = *reinterpret_cast<const float4*>(wi + (size_t)(g & 32767) * 4);
    float cs = cs_final[(h << 9) + k];
    float4 o;
    o.x = (DECAYF * w4.x + OMDF * d4.x) / cs;
    o.y = (DECAYF * w4.y + OMDF * d4.y) / cs;
    o.z = (DECAYF * w4.z + OMDF * d4.z) / cs;
    o.w = (DECAYF * w4.w + OMDF * d4.w) / cs;
    *reinterpret_cast<float4*>(new_emb + (size_t)g * 4) = o;
}

// ---------------- E: gather + output + vq_loss ----------------
__global__ __launch_bounds__(256) void vq_out(const float* __restrict__ x,
                                              const float* __restrict__ nemb,
                                              const int* __restrict__ idx,
                                              float* __restrict__ out) {
    __shared__ int idx_l[2][64];
    __shared__ float wsum[4];
    const int tid = threadIdx.x;
    const int b = blockIdx.x >> 5;
    const int t0 = (blockIdx.x & 31) << 6;
    if (tid < 128) {
        int hh = tid >> 6, t = tid & 63;
        idx_l[hh][t] = idx[hh * NROWS + b * TT + t0 + t];
    }
    __syncthreads();
    const int tq = tid & 15;
    const int cw = tid >> 4;
    const int k0 = idx_l[0][tq * 4 + 0], k1 = idx_l[0][tq * 4 + 1];
    const int k2 = idx_l[0][tq * 4 + 2], k3 = idx_l[0][tq * 4 + 3];
    const int m0 = idx_l[1][tq * 4 + 0], m1 = idx_l[1][tq * 4 + 1];
    const int m2 = idx_l[1][tq * 4 + 2], m3 = idx_l[1][tq * 4 + 3];
    float lsum = 0.f;
    for (int i = 0; i < 32; ++i) {
        const int c = cw + i * 16;
        const int hh = c >> 8, cp = c & 255;
        const size_t base = ((size_t)b * BD + c) * TT + t0 + tq * 4;
        float4 xv = *reinterpret_cast<const float4*>(x + base);
        const size_t eb = (size_t)(hh << 9) * SUBD + cp;
        float q0 = nemb[eb + (size_t)(hh ? m0 : k0) * SUBD];
        float q1 = nemb[eb + (size_t)(hh ? m1 : k1) * SUBD];
        float q2 = nemb[eb + (size_t)(hh ? m2 : k2) * SUBD];
        float q3 = nemb[eb + (size_t)(hh ? m3 : k3) * SUBD];
        float4 o; float t1;
        t1 = q0 - xv.x; o.x = xv.x + t1; lsum += t1 * t1;
        t1 = q1 - xv.y; o.y = xv.y + t1; lsum += t1 * t1;
        t1 = q2 - xv.z; o.z = xv.z + t1; lsum += t1 * t1;
        t1 = q3 - xv.w; o.w = xv.w + t1; lsum += t1 * t1;
        *reinterpret_cast<float4*>(out + base) = o;
    }
#pragma unroll
    for (int m = 1; m < 64; m <<= 1) lsum += __shfl_xor(lsum, m);
    if ((tid & 63) == 0) wsum[tid >> 6] = lsum;
    __syncthreads();
    if (tid == 0) {
        float s = wsum[0] + wsum[1] + wsum[2] + wsum[3];
        atomicAdd(out + 33554432, s * (0.25f / 33554432.0f));
    }
}

extern "C" void kernel_launch(void* const* d_in, const int* in_sizes, int n_in,
                              void* d_out, int out_size, void* d_ws, size_t ws_size,
                              hipStream_t stream) {
    const float* x    = (const float*)d_in[0];
    const float* emb1 = (const float*)d_in[1];
    const float* emb2 = (const float*)d_in[2];
    const float* cs1  = (const float*)d_in[3];
    const float* w1   = (const float*)d_in[4];
    const float* cs2  = (const float*)d_in[5];
    const float* w2   = (const float*)d_in[6];
    float* out = (float*)d_out;
    float* ws  = (float*)d_ws;

    float* counts = ws;                     // 1024
    float* csf    = ws + 1024;              // 1024
    float* se2    = ws + 2048;              // 1024
    float* nemb   = ws + 3072;              // 262144
    int*   idx    = (int*)(ws + 265216);    // 131072 ints
    uint4* embst  = (uint4*)(ws + 396288);  // 65536 uint4 (1 MB)
    float* f2g    = ws + 658432;            // 131072
    uint4* planeH = (uint4*)(ws + 789504);  // 4M uint4 (64 MB)
    uint4* planeL = (uint4*)(ws + 17566720);// 4M uint4 (64 MB)
    float* dw     = ws + 789504;            // fallback only (overlaps planeH)

    const size_t NEED = (size_t)(789504 + 2 * 16777216) * 4;
    const bool fast = (ws_size >= NEED);

    hipMemsetAsync(counts, 0, 1024 * sizeof(float), stream);
    hipMemsetAsync(out + 33554432, 0, 2 * sizeof(float), stream);

    vq_sume2 <<<4,   256, 0, stream>>>(emb1, emb2, se2);
    vq_embcvt<<<256, 256, 0, stream>>>(emb1, emb2, embst);

    if (fast) {
        vq_x1     <<<2048, 512, 0, stream>>>(x, planeH, planeL, f2g);
        vq_argmin4<<<2048, 512, 0, stream>>>(planeH, planeL, embst, f2g, se2, counts, idx);
        vq_stats  <<<1,    512, 0, stream>>>(counts, cs1, cs2, csf, out);
        vq_dwseg2 <<<1024, 256, 0, stream>>>(planeH, planeL, idx, w1, w2, csf, nemb);
    } else {
        hipMemsetAsync(dw, 0, 262144 * sizeof(float), stream);
        vq_argmin3<<<2048, 512, 0, stream>>>(x, embst, se2, counts, idx);
        vq_dw     <<<128,  256, 0, stream>>>(x, idx, dw);
        vq_stats  <<<1,    512, 0, stream>>>(counts, cs1, cs2, csf, out);
        vq_newemb <<<256,  256, 0, stream>>>(dw, w1, w2, csf, nemb);
    }
    vq_out<<<1024, 256, 0, stream>>>(x, nemb, idx, out);
}